// Round 7
// baseline (221.627 us; speedup 1.0000x reference)
//
#include <hip/hip_runtime.h>
#include <math.h>

#define B_ 16
#define C_ 384
#define N_ 1024
#define K_ 9

typedef _Float16 f16x8 __attribute__((ext_vector_type(8)));
typedef _Float16 f16x4 __attribute__((ext_vector_type(4)));
typedef float f32x4 __attribute__((ext_vector_type(4)));
typedef unsigned long long u64;

__device__ __forceinline__ void gld_lds16(const void* g, void* l) {
  __builtin_amdgcn_global_load_lds((const __attribute__((address_space(1))) void*)g,
                                   (__attribute__((address_space(3))) void*)l, 16, 0, 0);
}

// ---------------- transpose + fp16 split: x[b][c][n] -> xhT/xlT [b][n][c] ----------------
__global__ void k_cvt(const float* __restrict__ x, ushort* __restrict__ xhT,
                      ushort* __restrict__ xlT) {
  const int bid = blockIdx.x;  // ((b*16 + nt)*12 + ct)
  const int ct = bid % 12;
  const int nt = (bid / 12) & 15;
  const int b = bid / 192;
  const int c0 = ct * 32, n0 = nt * 64;
  __shared__ float ld[32 * 65];
  const int t = threadIdx.x;
  {
    const int c = t >> 3, n8 = (t & 7) * 8;
    const float* src = x + ((size_t)(b * C_ + c0 + c) * N_ + n0 + n8);
    float4 v0 = *(const float4*)src;
    float4 v1 = *(const float4*)(src + 4);
    float vv[8] = {v0.x, v0.y, v0.z, v0.w, v1.x, v1.y, v1.z, v1.w};
#pragma unroll
    for (int j = 0; j < 8; ++j) ld[c * 65 + n8 + j] = vv[j];
  }
  __syncthreads();
  {
    const int n = t >> 2, c8 = (t & 3) * 8;
    f16x8 hv, lv;
#pragma unroll
    for (int j = 0; j < 8; ++j) {
      float v = ld[(c8 + j) * 65 + n];
      _Float16 h = (_Float16)v;
      _Float16 l = (_Float16)(v - (float)h);
      hv[j] = h;
      lv[j] = l;
    }
    const size_t off = (size_t)(b * N_ + n0 + n) * C_ + c0 + c8;
    *(f16x8*)(xhT + off) = hv;
    *(f16x8*)(xlT + off) = lv;
  }
}

// ---------------- Wg -> WgH/WgL ----------------
__global__ void k_cvtw(const float* __restrict__ Wg, ushort* __restrict__ WgH,
                       ushort* __restrict__ WgL) {
  const int i = (blockIdx.x * 256 + threadIdx.x) * 4;  // 144 blocks
  float4 v = *(const float4*)(Wg + i);
  float vv[4] = {v.x, v.y, v.z, v.w};
  f16x4 hv, lv;
#pragma unroll
  for (int j = 0; j < 4; ++j) {
    _Float16 h = (_Float16)vv[j];
    hv[j] = h;
    lv[j] = (_Float16)(vv[j] - (float)h);
  }
  *(f16x4*)(WgH + i) = hv;
  *(f16x4*)(WgL + i) = lv;
}

// ---------------- sq pass 1: partial sums over 24-channel chunks (fp64) ----------------
__global__ void k_sq1(const float* __restrict__ x, double* __restrict__ part) {
  const int bid = blockIdx.x;
  const int b = bid >> 6, q = (bid >> 2) & 15, nt = bid & 3;
  const int n = nt * 256 + threadIdx.x;
  const float* xb = x + ((size_t)b * C_ + q * 24) * N_ + n;
  double s = 0.0;
#pragma unroll 4
  for (int c = 0; c < 24; ++c) {
    float v = xb[(size_t)c * N_];
    s = fma((double)v, (double)v, s);
  }
  part[((size_t)b * 16 + q) * N_ + n] = s;
}

// ---------------- sq pass 2: deterministic reduce of 16 partials ----------------
__global__ void k_sq2(const double* __restrict__ part, float* __restrict__ sq) {
  const int idx = blockIdx.x * blockDim.x + threadIdx.x;
  const int b = idx >> 10, n = idx & 1023;
  const double* p = part + (size_t)b * 16 * N_ + n;
  double s = 0.0;
#pragma unroll
  for (int q = 0; q < 16; ++q) s += p[(size_t)q * N_];
  sq[idx] = (float)s;
}

__device__ __forceinline__ void ce2f(float& a, float& b) {
  float lo = fminf(a, b), hi = fmaxf(a, b);
  a = lo;
  b = hi;
}
__device__ __forceinline__ void ce9u(u64& a, u64& b) {
  u64 lo = a < b ? a : b;
  u64 hi = a < b ? b : a;
  a = lo;
  b = hi;
}
// merge two sorted 9-lists (in-register, no shuffle): bitonic pick + 13-CE cleanup
__device__ __forceinline__ void mrg9(float* a, const float* b) {
  float m[9];
#pragma unroll
  for (int k = 0; k < 9; ++k) m[k] = fminf(a[k], b[8 - k]);
  ce2f(m[0], m[8]);
  ce2f(m[1], m[5]); ce2f(m[2], m[6]); ce2f(m[3], m[7]); ce2f(m[4], m[8]);
  ce2f(m[1], m[3]); ce2f(m[2], m[4]); ce2f(m[5], m[7]); ce2f(m[6], m[8]);
  ce2f(m[1], m[2]); ce2f(m[3], m[4]); ce2f(m[5], m[6]); ce2f(m[7], m[8]);
#pragma unroll
  for (int k = 0; k < 9; ++k) a[k] = m[k];
}

// ---------------- fused MFMA Gram + per-tile top-9: D never hits HBM ----------------
// R2-proven GEMM core (dbuf 2x32KB, prefetch-1, XCD batch grouping), swapped mfma
// operands (rows=m, cols=q; bitwise-identical distances). Epilogue v3 (spill-free):
// d -> LDS[q][m^swz] (64KB), then per row (2 lanes/row, 64 vals/lane) top-9 via FOUR
// independent 16-elem insertion chains (4x ILP, 36 key VGPRs, values NOT kept in regs
// -> no scratch spill; R6's v[64] spilled and cost ~25us of scratch latency) + 3
// in-register list merges + 1 shuffle merge. Masks re-read LDS; emit as R6.
__global__ __launch_bounds__(256, 2) void k_gram(const ushort* __restrict__ xhT,
                                                 const ushort* __restrict__ xlT,
                                                 const float* __restrict__ sq,
                                                 u64* __restrict__ part, int base_b, int nb) {
  const int bid = blockIdx.x;
  int b_local, pid;
  if (nb >= 8) {
    const int x = bid & 7, j = bid >> 3, grp = nb >> 3;
    b_local = x * grp + (j >> 6);
    pid = j & 63;
  } else {
    b_local = bid >> 6;
    pid = bid & 63;
  }
  const int b = base_b + b_local;
  const int rt = pid >> 3, mt = pid & 7;
  const int n0 = rt * 128, m0 = mt * 128;

  __shared__ alignas(16) char sm[2][32768];
  const int t = threadIdx.x;
  const int lane = t & 63, wid = t >> 6, quad = lane >> 4, lrow = lane & 15;
  const int wr = wid >> 1, wc = wid & 1;
  const int lrow4 = lane >> 2, lpos = lane & 3;

  // wave -> array it stages: 0:Ah(n0,h) 1:Al(n0,l) 2:Bh(m0,h) 3:Bl(m0,l)
  const char* src = (const char*)((wid & 1) ? xlT : xhT) +
                    (size_t)(b * N_ + ((wid >> 1) ? m0 : n0)) * C_ * 2;

  f32x4 acc[4][4];
#pragma unroll
  for (int mi = 0; mi < 4; ++mi)
#pragma unroll
    for (int ni = 0; ni < 4; ++ni) acc[mi][ni] = (f32x4){0.f, 0.f, 0.f, 0.f};

  auto stage = [&](int it) {
    char* dst = sm[it & 1] + wid * 8192;
    const int ktB = it * 64;
#pragma unroll
    for (int i = 0; i < 8; ++i) {
      const int row = i * 16 + lrow4;
      const int swz = lpos ^ ((row >> 1) & 3);
      gld_lds16(src + (size_t)row * 768 + ktB + swz * 16, dst + i * 1024 + lane * 16);
    }
  };

  stage(0);
  for (int it = 0; it < 12; ++it) {
    __syncthreads();
    if (it < 11) stage(it + 1);
    const char* smb = sm[it & 1];
    f16x8 ah[4], al[4];
#pragma unroll
    for (int mi = 0; mi < 4; ++mi) {
      const int row = wr * 64 + mi * 16 + lrow;
      const int off = row * 64 + (quad ^ ((row >> 1) & 3)) * 16;
      ah[mi] = *(const f16x8*)(smb + off);
      al[mi] = *(const f16x8*)(smb + 8192 + off);
    }
#pragma unroll
    for (int ni = 0; ni < 4; ++ni) {
      const int row = wc * 64 + ni * 16 + lrow;
      const int off = row * 64 + (quad ^ ((row >> 1) & 3)) * 16;
      f16x8 bh = *(const f16x8*)(smb + 16384 + off);
      f16x8 bl = *(const f16x8*)(smb + 24576 + off);
#pragma unroll
      for (int mi = 0; mi < 4; ++mi) {
        // swapped operands: rows=m (bh tile), cols=q (ah tile)
        acc[mi][ni] = __builtin_amdgcn_mfma_f32_16x16x32_f16(bh, ah[mi], acc[mi][ni], 0, 0, 0);
        acc[mi][ni] = __builtin_amdgcn_mfma_f32_16x16x32_f16(bh, al[mi], acc[mi][ni], 0, 0, 0);
        acc[mi][ni] = __builtin_amdgcn_mfma_f32_16x16x32_f16(bl, ah[mi], acc[mi][ni], 0, 0, 0);
      }
    }
  }
  __syncthreads();  // all mfma LDS reads done before the transpose buffer overwrites sm

  // acc[mi][ni][r]: m_local = wc*64+ni*16+quad*4+r, q_local = wr*64+mi*16+lrow
  const float* sqb = sq + b * N_;
  float sqm_[4][4];
#pragma unroll
  for (int ni = 0; ni < 4; ++ni)
#pragma unroll
    for (int r = 0; r < 4; ++r) sqm_[ni][r] = sqb[m0 + wc * 64 + ni * 16 + quad * 4 + r];
  float sqq_[4];
#pragma unroll
  for (int mi = 0; mi < 4; ++mi) sqq_[mi] = sqb[n0 + wr * 64 + mi * 16 + lrow];

  float* smf = (float*)sm;  // 128 q-rows x 128 m-cols, 16B-chunk XOR swizzle per row
#pragma unroll
  for (int mi = 0; mi < 4; ++mi) {
    const int qL = wr * 64 + mi * 16 + lrow;
    const int qG = n0 + qL;
#pragma unroll
    for (int ni = 0; ni < 4; ++ni) {
      const int tc = wc * 16 + ni * 4 + quad;      // true chunk (4 f32)
      const int stv = tc ^ (qL & 31);              // stored chunk
      f32x4 dv;
#pragma unroll
      for (int r = 0; r < 4; ++r) {
        const int mG = m0 + wc * 64 + ni * 16 + quad * 4 + r;
        float d = fmaf(-2.f, acc[mi][ni][r], sqq_[mi] + sqm_[ni][r]);
        if (mG == qG) d = 3.402823466e38f;
        dv[r] = d;
      }
      *(f32x4*)(smf + qL * 128 + stv * 4) = dv;
    }
  }
  __syncthreads();

  // selection: wave wid owns q rows [wid*32, wid*32+32); 2 lanes/row, 64 values/lane.
  // 4 independent 16-elem chains (read LDS, consume, discard - nothing kept in regs).
  const int qsel = wid * 32 + (lane & 31);
  const int half = lane >> 5;
  float kA[9], kB[9], kC[9], kD[9];
#pragma unroll
  for (int k = 0; k < 9; ++k) kA[k] = kB[k] = kC[k] = kD[k] = 3.402823466e38f;

  auto ins16 = [&](float* key, int tcb) {
#pragma unroll
    for (int i = 0; i < 4; ++i) {
      const int tc = tcb + i;
      const int stv = tc ^ (qsel & 31);
      f32x4 q4 = *(const f32x4*)(smf + qsel * 128 + stv * 4);
#pragma unroll
      for (int e = 0; e < 4; ++e) {
        key[8] = fminf(key[8], q4[e]);
#pragma unroll
        for (int s = 8; s >= 1; --s) ce2f(key[s - 1], key[s]);
      }
    }
  };
  ins16(kA, half * 16 + 0);
  ins16(kB, half * 16 + 4);
  ins16(kC, half * 16 + 8);
  ins16(kD, half * 16 + 12);
  mrg9(kA, kB);
  mrg9(kC, kD);
  mrg9(kA, kC);
  {  // merge the two half-lists across lanes (bitonic trick + 13-CE cleanup)
    float pk[9];
#pragma unroll
    for (int k = 0; k < 9; ++k) pk[k] = __shfl_xor(kA[k], 32, 64);
    float m[9];
#pragma unroll
    for (int k = 0; k < 9; ++k) m[k] = fminf(kA[k], pk[8 - k]);
    ce2f(m[0], m[8]);
    ce2f(m[1], m[5]); ce2f(m[2], m[6]); ce2f(m[3], m[7]); ce2f(m[4], m[8]);
    ce2f(m[1], m[3]); ce2f(m[2], m[4]); ce2f(m[5], m[7]); ce2f(m[6], m[8]);
    ce2f(m[1], m[2]); ce2f(m[3], m[4]); ce2f(m[5], m[6]); ce2f(m[7], m[8]);
#pragma unroll
    for (int k = 0; k < 9; ++k) kA[k] = m[k];
  }
  const float v9 = kA[8];
  int c_lt = 0;
#pragma unroll
  for (int k = 0; k < 8; ++k) c_lt += (kA[k] < v9) ? 1 : 0;

  // mask pass: re-read the 16 chunks from LDS (cheaper than 64 VGPRs of kept values)
  u64 lt_mask = 0ull, eq_mask = 0ull;
#pragma unroll
  for (int i = 0; i < 16; ++i) {
    const int tc = half * 16 + i;
    const int stv = tc ^ (qsel & 31);
    f32x4 q4 = *(const f32x4*)(smf + qsel * 128 + stv * 4);
#pragma unroll
    for (int e = 0; e < 4; ++e) {
      const int j = i * 4 + e;
      lt_mask |= (q4[e] < v9) ? (1ull << j) : 0ull;
      eq_mask |= (q4[e] == v9) ? (1ull << j) : 0ull;
    }
  }
  const int ltc = __popcll(lt_mask), eqc = __popcll(eq_mask);
  const int packed = ltc | (eqc << 16);
  const int other = __shfl_xor(packed, 32, 64);
  const int lt_pref = half ? (other & 0xFFFF) : 0;
  const int eq_pref = half ? (other >> 16) : 0;

  u64* pp = part + ((size_t)(b_local * N_ + n0 + qsel) * 8 + mt) * 9;
  int slot = lt_pref;
  u64 msk = lt_mask;
  while (msk) {
    const int j = __builtin_ctzll(msk);
    msk &= msk - 1;
    const int mL = half * 64 + j;
    const int stv = (mL >> 2) ^ (qsel & 31);
    const float val = smf[qsel * 128 + stv * 4 + (mL & 3)];  // runtime idx -> LDS re-read
    unsigned fb = __float_as_uint(val);
    unsigned mono = (fb >> 31) ? ~fb : (fb | 0x80000000u);
    pp[slot++] = ((u64)mono << 32) | (unsigned)(m0 + mL);
  }
  unsigned fb9 = __float_as_uint(v9);
  unsigned mono9 = (fb9 >> 31) ? ~fb9 : (fb9 | 0x80000000u);
  slot = c_lt + eq_pref;
  msk = eq_mask;
  while (msk && slot < 9) {
    const int j = __builtin_ctzll(msk);
    msk &= msk - 1;
    pp[slot++] = ((u64)mono9 << 32) | (unsigned)(m0 + half * 64 + j);
  }
}

// ---------------- merge 8 per-segment top-9s per node -> nbr ----------------
__global__ void k_mrg(const u64* __restrict__ part, int* __restrict__ nbr, int base_node) {
  const int nl = blockIdx.x * 256 + threadIdx.x;
  const u64* p = part + (size_t)nl * 72;
  u64 key[9];
#pragma unroll
  for (int k = 0; k < 9; ++k) key[k] = ~0ull;
#pragma unroll 4
  for (int j = 0; j < 72; ++j) {
    u64 kk = p[j];
    key[8] = key[8] < kk ? key[8] : kk;
#pragma unroll
    for (int s = 8; s >= 1; --s) ce9u(key[s - 1], key[s]);
  }
  int* np = nbr + (size_t)(base_node + nl) * K_;
#pragma unroll
  for (int k = 0; k < 9; ++k) np[k] = (int)(unsigned)(key[k] & 0xFFFFFFFFu);
}

// ---------------- MFMA xw[b][co][n]: A=Wg(h/l), B=xT(h/l), dbuf staging ----------------
__global__ __launch_bounds__(256, 3) void k_xw(const ushort* __restrict__ xhT,
                                               const ushort* __restrict__ xlT,
                                               const ushort* __restrict__ WgH,
                                               const ushort* __restrict__ WgL,
                                               float* __restrict__ xw) {
  const int bid = blockIdx.x;
  const int xcd = bid & 7, j = bid >> 3;   // 96 blocks per XCD
  const int pair = xcd * 16 + j / 6;       // (b,nt) pair; 6 consecutive j share it
  const int ct = j % 6;
  const int b = pair >> 3, nt = pair & 7;
  const int co0 = ct * 64, n0 = nt * 128;
  __shared__ alignas(16) char sm[2][24576];  // per buf: Ah@0 Al@4096 Bh@8192 Bl@16384
  const int t = threadIdx.x;
  const int lane = t & 63, wid = t >> 6, quad = lane >> 4, lrow = lane & 15;
  const int wr = wid >> 1, wc = wid & 1;
  const int lrow4 = lane >> 2, lpos = lane & 3;

  f32x4 acc[2][4];
#pragma unroll
  for (int mi = 0; mi < 2; ++mi)
#pragma unroll
    for (int ni = 0; ni < 4; ++ni) acc[mi][ni] = (f32x4){0.f, 0.f, 0.f, 0.f};

  const char* asrc[2] = {(const char*)(WgH + (size_t)co0 * C_),
                         (const char*)(WgL + (size_t)co0 * C_)};
  const char* bsrc[2] = {(const char*)(xhT + (size_t)(b * N_ + n0) * C_),
                         (const char*)(xlT + (size_t)(b * N_ + n0) * C_)};

  auto stage = [&](int it) {
    char* dst = sm[it & 1];
    const int ktB = it * 64;
#pragma unroll
    for (int i = 0; i < 6; ++i) {
      const int c = wid * 6 + i;
      const char* src;
      int base, row;
      if (c < 8) {
        const int arr = c >> 2, sub = c & 3;
        src = asrc[arr];
        base = arr * 4096 + sub * 1024;
        row = sub * 16 + lrow4;
      } else {
        const int cc = c - 8, arr = cc >> 3, sub = cc & 7;
        src = bsrc[arr];
        base = 8192 + arr * 8192 + sub * 1024;
        row = sub * 16 + lrow4;
      }
      const int swz = lpos ^ ((row >> 1) & 3);
      gld_lds16(src + (size_t)row * 768 + ktB + swz * 16, dst + base + lane * 16);
    }
  };

  stage(0);
  for (int it = 0; it < 12; ++it) {
    __syncthreads();
    if (it < 11) stage(it + 1);
    const char* smb = sm[it & 1];
    f16x8 bh[4], bl[4];
#pragma unroll
    for (int ni = 0; ni < 4; ++ni) {
      const int row = wr * 64 + ni * 16 + lrow;
      const int off = row * 64 + (quad ^ ((row >> 1) & 3)) * 16;
      bh[ni] = *(const f16x8*)(smb + 8192 + off);
      bl[ni] = *(const f16x8*)(smb + 16384 + off);
    }
#pragma unroll
    for (int mi = 0; mi < 2; ++mi) {
      const int row = wc * 32 + mi * 16 + lrow;
      const int off = row * 64 + (quad ^ ((row >> 1) & 3)) * 16;
      f16x8 ah = *(const f16x8*)(smb + off);
      f16x8 al = *(const f16x8*)(smb + 4096 + off);
#pragma unroll
      for (int ni = 0; ni < 4; ++ni) {
        acc[mi][ni] = __builtin_amdgcn_mfma_f32_16x16x32_f16(ah, bh[ni], acc[mi][ni], 0, 0, 0);
        acc[mi][ni] = __builtin_amdgcn_mfma_f32_16x16x32_f16(al, bh[ni], acc[mi][ni], 0, 0, 0);
        acc[mi][ni] = __builtin_amdgcn_mfma_f32_16x16x32_f16(ah, bl[ni], acc[mi][ni], 0, 0, 0);
      }
    }
  }
#pragma unroll
  for (int mi = 0; mi < 2; ++mi)
#pragma unroll
    for (int ni = 0; ni < 4; ++ni)
#pragma unroll
      for (int r = 0; r < 4; ++r) {
        const int c_g = co0 + wc * 32 + mi * 16 + quad * 4 + r;
        const int n_g = n0 + wr * 64 + ni * 16 + lrow;
        xw[((size_t)b * C_ + c_g) * N_ + n_g] = acc[mi][ni][r];
      }
}

// ---------------- aggregate (deg==10 uniformly) + BN partial stats ----------------
__global__ __launch_bounds__(256) void k_agg(const float* __restrict__ xw,
                                             const int* __restrict__ nbr,
                                             const float* __restrict__ bg,
                                             float* __restrict__ out,
                                             float* __restrict__ stats) {
  const int ct = blockIdx.x % (C_ / 8);  // 48
  const int b = blockIdx.x / (C_ / 8);
  const int c0 = ct * 8;
  __shared__ alignas(16) int nb_l[N_ * K_];       // 36864 B
  __shared__ alignas(16) float row_l[8][N_ + 4];  // 32896 B
  __shared__ float red[2][8][4];
  const int tid = threadIdx.x;
  const int4* gp = (const int4*)(nbr + (size_t)b * N_ * K_);
  int4* lp = (int4*)nb_l;
  for (int t = tid; t < N_ * K_ / 4; t += 256) lp[t] = gp[t];
  for (int t = tid; t < 8 * (N_ / 4); t += 256) {
    const int j = t >> 8, n4 = t & 255;  // N_/4 = 256
    float4 v = ((const float4*)(xw + ((size_t)(b * C_ + c0 + j)) * N_))[n4];
    *(float4*)&row_l[j][n4 * 4] = v;
  }
  __syncthreads();
  float bgc[8];
#pragma unroll
  for (int j = 0; j < 8; ++j) bgc[j] = bg[c0 + j];
  float s1[8], s2[8];
#pragma unroll
  for (int j = 0; j < 8; ++j) {
    s1[j] = 0.f;
    s2[j] = 0.f;
  }
  float* outb = out + ((size_t)b * C_ + c0) * N_;
#pragma unroll
  for (int s = 0; s < 4; ++s) {
    const int n = tid + 256 * s;
    const int* nn_ = &nb_l[n * K_];
    int idx[K_];
#pragma unroll
    for (int k = 0; k < K_; ++k) idx[k] = nn_[k];
    float a[8];
#pragma unroll
    for (int j = 0; j < 8; ++j) a[j] = row_l[j][n];
#pragma unroll
    for (int k = 0; k < K_; ++k) {
      const int m = idx[k];
#pragma unroll
      for (int j = 0; j < 8; ++j) a[j] += row_l[j][m];
    }
#pragma unroll
    for (int j = 0; j < 8; ++j) {
      float y = fmaf(a[j], 0.099999994f, bgc[j]);
      outb[(size_t)j * N_ + n] = y;
      s1[j] += y;
      s2[j] = fmaf(y, y, s2[j]);
    }
  }
#pragma unroll
  for (int off = 32; off > 0; off >>= 1)
#pragma unroll
    for (int j = 0; j < 8; ++j) {
      s1[j] += __shfl_down(s1[j], off, 64);
      s2[j] += __shfl_down(s2[j], off, 64);
    }
  const int lane = tid & 63, wid = tid >> 6;
  if (lane == 0)
#pragma unroll
    for (int j = 0; j < 8; ++j) {
      red[0][j][wid] = s1[j];
      red[1][j][wid] = s2[j];
    }
  __syncthreads();
  if (tid < 16) {
    const int j = tid & 7, which = tid >> 3;
    float v = red[which][j][0] + red[which][j][1] + red[which][j][2] + red[which][j][3];
    atomicAdd(&stats[which * C_ + c0 + j], v);
  }
}

// ---------------- BN (batch stats) + tanh-GELU + residual ----------------
__global__ void k_bn(const float* __restrict__ x, const float* __restrict__ gamma,
                     const float* __restrict__ beta, const float* __restrict__ stats,
                     float* __restrict__ out) {
  const int f = blockIdx.x * blockDim.x + threadIdx.x;
  const int e = f * 4;
  const int c = (e >> 10) % C_;
  const float inv = 1.f / 16384.f;
  const float mu = stats[c] * inv;
  const float var = fmaf(-mu, mu, stats[C_ + c] * inv);
  const float sc = gamma[c] * rsqrtf(var + 1e-5f);
  const float sh = fmaf(-mu, sc, beta[c]);
  float4 y = ((const float4*)out)[f];
  float4 xv = ((const float4*)x)[f];
  auto gl = [](float z) {
    float z3 = z * z * z;
    float t = 0.7978845608028654f * fmaf(0.044715f, z3, z);
    float th = tanhf(t);
    return 0.5f * z * (1.f + th);
  };
  float4 o;
  o.x = gl(fmaf(y.x, sc, sh)) + xv.x;
  o.y = gl(fmaf(y.y, sc, sh)) + xv.y;
  o.z = gl(fmaf(y.z, sc, sh)) + xv.z;
  o.w = gl(fmaf(y.w, sc, sh)) + xv.w;
  ((float4*)out)[f] = o;
}

extern "C" void kernel_launch(void* const* d_in, const int* in_sizes, int n_in,
                              void* d_out, int out_size, void* d_ws, size_t ws_size,
                              hipStream_t stream) {
  const float* x = (const float*)d_in[0];
  const float* Wg = (const float*)d_in[1];
  const float* bg = (const float*)d_in[2];
  const float* gamma = (const float*)d_in[3];
  const float* beta = (const float*)d_in[4];
  float* out = (float*)d_out;

  // D eliminated -> full-batch footprint = 51,579,904 B (== proven R4 minimum): nb=16.
  const int nb = 16;

  char* ws = (char*)d_ws;
  ushort* xhT = (ushort*)ws;                  // @0          12,582,912
  ushort* xlT = (ushort*)(ws + 12582912);     //             12,582,912
  ushort* WgH = (ushort*)(ws + 25165824);     //                294,912
  ushort* WgL = (ushort*)(ws + 25460736);     //                294,912
  float* sq = (float*)(ws + 25755648);        //                 65,536
  u64* part = (u64*)(ws + 25821184);          // nb*589,824 (<= 9.4 MB)
  float* xw = (float*)(ws + 25821184);        // overlays part (part dead after k_mrg)
  double* sqpart = (double*)(ws + 25821184);  // overlays part head (dead before gram)
  size_t dreg = 25165824;                     // xw needs 25.17 MB
  int* nbr = (int*)(ws + 25821184 + dreg);    //                589,824
  float* stats = (float*)(ws + 25821184 + dreg + 589824);  //     3,072

  hipMemsetAsync(stats, 0, 2 * C_ * sizeof(float), stream);
  k_cvt<<<3072, 256, 0, stream>>>(x, xhT, xlT);
  k_cvtw<<<144, 256, 0, stream>>>(Wg, WgH, WgL);
  k_sq1<<<1024, 256, 0, stream>>>(x, sqpart);
  k_sq2<<<64, 256, 0, stream>>>(sqpart, sq);
  k_gram<<<nb * 64, 256, 0, stream>>>(xhT, xlT, sq, part, 0, nb);
  k_mrg<<<nb * 4, 256, 0, stream>>>(part, nbr, 0);
  k_xw<<<768, 256, 0, stream>>>(xhT, xlT, WgH, WgL, xw);
  k_agg<<<B_ * (C_ / 8), 256, 0, stream>>>(xw, nbr, bg, out, stats);
  k_bn<<<6144, 256, 0, stream>>>(x, gamma, beta, stats, out);
}

// Round 8
// 220.456 us; speedup vs baseline: 1.0053x; 1.0053x over previous
//
#include <hip/hip_runtime.h>
#include <math.h>

#define B_ 16
#define C_ 384
#define N_ 1024
#define K_ 9

typedef _Float16 f16x8 __attribute__((ext_vector_type(8)));
typedef _Float16 f16x4 __attribute__((ext_vector_type(4)));
typedef float f32x4 __attribute__((ext_vector_type(4)));
typedef unsigned long long u64;

__device__ __forceinline__ void gld_lds16(const void* g, void* l) {
  __builtin_amdgcn_global_load_lds((const __attribute__((address_space(1))) void*)g,
                                   (__attribute__((address_space(3))) void*)l, 16, 0, 0);
}

// ---------------- fused front-end: transpose+fp16 split + sq + Wg split + stats0 -------
// blocks 0..511: (b, 32-node slice). All 384 channels staged in LDS (padded [384][33]),
// so each output row (768B) is written by ONE block as 6 full 128B lines (old version
// wrote 12x64B fragments from 12 blocks on different XCDs -> HBM partial-line write
// amplification). sq computed in-block from the staged tile (fp64, deterministic
// 48-chunk + 8-lane xor tree) -> the separate 25MB x re-read (k_sq1/k_sq2) is gone.
// blocks 512..655: Wg -> WgH/WgL (+ block 512 zeroes stats, replacing the memset).
__global__ __launch_bounds__(256) void k_cvt(const float* __restrict__ x,
                                             const float* __restrict__ Wg,
                                             ushort* __restrict__ xhT, ushort* __restrict__ xlT,
                                             float* __restrict__ sq, ushort* __restrict__ WgH,
                                             ushort* __restrict__ WgL,
                                             float* __restrict__ stats) {
  const int bid = blockIdx.x;
  const int t = threadIdx.x;
  if (bid >= 512) {  // ---- Wg split (144 blocks) + stats zero ----
    const int i = ((bid - 512) * 256 + t) * 4;
    float4 v = *(const float4*)(Wg + i);
    float vv[4] = {v.x, v.y, v.z, v.w};
    f16x4 hv, lv;
#pragma unroll
    for (int j = 0; j < 4; ++j) {
      _Float16 h = (_Float16)vv[j];
      hv[j] = h;
      lv[j] = (_Float16)(vv[j] - (float)h);
    }
    *(f16x4*)(WgH + i) = hv;
    *(f16x4*)(WgL + i) = lv;
    if (bid == 512) {
      stats[t] = 0.f;
      stats[t + 256] = 0.f;
      stats[t + 512] = 0.f;
    }
    return;
  }
  const int b = bid >> 5, n0 = (bid & 31) * 32;
  __shared__ float ld[384 * 33];  // 50688 B; bank(c*33+n) = (c+n)%32
  {
    const int cb = t >> 2, j8 = (t & 3) * 8;
#pragma unroll
    for (int i = 0; i < 6; ++i) {
      const int c = i * 64 + cb;
      const float* src = x + ((size_t)(b * C_ + c) * N_ + n0 + j8);
      float4 v0 = *(const float4*)src;
      float4 v1 = *(const float4*)(src + 4);
      float* dst = &ld[c * 33 + j8];
      dst[0] = v0.x; dst[1] = v0.y; dst[2] = v0.z; dst[3] = v0.w;
      dst[4] = v1.x; dst[5] = v1.y; dst[6] = v1.z; dst[7] = v1.w;
    }
  }
  __syncthreads();
  {
    const int n = t >> 3, l = t & 7;
    // transpose + split: chunk i -> 8 lanes x 16B = one 128B line, fully coalesced
#pragma unroll
    for (int i = 0; i < 6; ++i) {
      const int c8 = i * 64 + l * 8;
      f16x8 hv, lv;
#pragma unroll
      for (int j = 0; j < 8; ++j) {
        float v = ld[(c8 + j) * 33 + n];
        _Float16 h = (_Float16)v;
        hv[j] = h;
        lv[j] = (_Float16)(v - (float)h);
      }
      const size_t off = (size_t)(b * N_ + n0 + n) * C_ + c8;
      *(f16x8*)(xhT + off) = hv;
      *(f16x8*)(xlT + off) = lv;
    }
    // sq: fp64 48-channel chunk per lane, balanced xor-tree over the 8-lane group
    double s = 0.0;
    const int cbase = l * 48;
#pragma unroll
    for (int cc = 0; cc < 48; ++cc) {
      float v = ld[(cbase + cc) * 33 + n];
      s = fma((double)v, (double)v, s);
    }
    s += __shfl_xor(s, 1, 64);
    s += __shfl_xor(s, 2, 64);
    s += __shfl_xor(s, 4, 64);
    if (l == 0) sq[b * N_ + n0 + n] = (float)s;
  }
}

__device__ __forceinline__ void ce2f(float& a, float& b) {
  float lo = fminf(a, b), hi = fmaxf(a, b);
  a = lo;
  b = hi;
}
__device__ __forceinline__ void ce9u(u64& a, u64& b) {
  u64 lo = a < b ? a : b;
  u64 hi = a < b ? b : a;
  a = lo;
  b = hi;
}
// merge two sorted 9-lists (in-register, no shuffle): bitonic pick + 13-CE cleanup
__device__ __forceinline__ void mrg9(float* a, const float* b) {
  float m[9];
#pragma unroll
  for (int k = 0; k < 9; ++k) m[k] = fminf(a[k], b[8 - k]);
  ce2f(m[0], m[8]);
  ce2f(m[1], m[5]); ce2f(m[2], m[6]); ce2f(m[3], m[7]); ce2f(m[4], m[8]);
  ce2f(m[1], m[3]); ce2f(m[2], m[4]); ce2f(m[5], m[7]); ce2f(m[6], m[8]);
  ce2f(m[1], m[2]); ce2f(m[3], m[4]); ce2f(m[5], m[6]); ce2f(m[7], m[8]);
#pragma unroll
  for (int k = 0; k < 9; ++k) a[k] = m[k];
}

// ---------------- fused MFMA Gram + per-tile top-9: D never hits HBM ----------------
// R2-proven GEMM core (dbuf 2x32KB, prefetch-1, XCD batch grouping), swapped mfma
// operands (rows=m, cols=q; bitwise-identical distances). Spill-free 4-chain epilogue
// (R7, 53.5us). part layout now [(b,seg)][node] for coalesced k_mrg reads.
__global__ __launch_bounds__(256, 2) void k_gram(const ushort* __restrict__ xhT,
                                                 const ushort* __restrict__ xlT,
                                                 const float* __restrict__ sq,
                                                 u64* __restrict__ part, int base_b, int nb) {
  const int bid = blockIdx.x;
  int b_local, pid;
  if (nb >= 8) {
    const int x = bid & 7, j = bid >> 3, grp = nb >> 3;
    b_local = x * grp + (j >> 6);
    pid = j & 63;
  } else {
    b_local = bid >> 6;
    pid = bid & 63;
  }
  const int b = base_b + b_local;
  const int rt = pid >> 3, mt = pid & 7;
  const int n0 = rt * 128, m0 = mt * 128;

  __shared__ alignas(16) char sm[2][32768];
  const int t = threadIdx.x;
  const int lane = t & 63, wid = t >> 6, quad = lane >> 4, lrow = lane & 15;
  const int wr = wid >> 1, wc = wid & 1;
  const int lrow4 = lane >> 2, lpos = lane & 3;

  // wave -> array it stages: 0:Ah(n0,h) 1:Al(n0,l) 2:Bh(m0,h) 3:Bl(m0,l)
  const char* src = (const char*)((wid & 1) ? xlT : xhT) +
                    (size_t)(b * N_ + ((wid >> 1) ? m0 : n0)) * C_ * 2;

  f32x4 acc[4][4];
#pragma unroll
  for (int mi = 0; mi < 4; ++mi)
#pragma unroll
    for (int ni = 0; ni < 4; ++ni) acc[mi][ni] = (f32x4){0.f, 0.f, 0.f, 0.f};

  auto stage = [&](int it) {
    char* dst = sm[it & 1] + wid * 8192;
    const int ktB = it * 64;
#pragma unroll
    for (int i = 0; i < 8; ++i) {
      const int row = i * 16 + lrow4;
      const int swz = lpos ^ ((row >> 1) & 3);
      gld_lds16(src + (size_t)row * 768 + ktB + swz * 16, dst + i * 1024 + lane * 16);
    }
  };

  stage(0);
  for (int it = 0; it < 12; ++it) {
    __syncthreads();
    if (it < 11) stage(it + 1);
    const char* smb = sm[it & 1];
    f16x8 ah[4], al[4];
#pragma unroll
    for (int mi = 0; mi < 4; ++mi) {
      const int row = wr * 64 + mi * 16 + lrow;
      const int off = row * 64 + (quad ^ ((row >> 1) & 3)) * 16;
      ah[mi] = *(const f16x8*)(smb + off);
      al[mi] = *(const f16x8*)(smb + 8192 + off);
    }
#pragma unroll
    for (int ni = 0; ni < 4; ++ni) {
      const int row = wc * 64 + ni * 16 + lrow;
      const int off = row * 64 + (quad ^ ((row >> 1) & 3)) * 16;
      f16x8 bh = *(const f16x8*)(smb + 16384 + off);
      f16x8 bl = *(const f16x8*)(smb + 24576 + off);
#pragma unroll
      for (int mi = 0; mi < 4; ++mi) {
        // swapped operands: rows=m (bh tile), cols=q (ah tile)
        acc[mi][ni] = __builtin_amdgcn_mfma_f32_16x16x32_f16(bh, ah[mi], acc[mi][ni], 0, 0, 0);
        acc[mi][ni] = __builtin_amdgcn_mfma_f32_16x16x32_f16(bh, al[mi], acc[mi][ni], 0, 0, 0);
        acc[mi][ni] = __builtin_amdgcn_mfma_f32_16x16x32_f16(bl, ah[mi], acc[mi][ni], 0, 0, 0);
      }
    }
  }
  __syncthreads();  // all mfma LDS reads done before the transpose buffer overwrites sm

  // acc[mi][ni][r]: m_local = wc*64+ni*16+quad*4+r, q_local = wr*64+mi*16+lrow
  const float* sqb = sq + b * N_;
  float sqm_[4][4];
#pragma unroll
  for (int ni = 0; ni < 4; ++ni)
#pragma unroll
    for (int r = 0; r < 4; ++r) sqm_[ni][r] = sqb[m0 + wc * 64 + ni * 16 + quad * 4 + r];
  float sqq_[4];
#pragma unroll
  for (int mi = 0; mi < 4; ++mi) sqq_[mi] = sqb[n0 + wr * 64 + mi * 16 + lrow];

  float* smf = (float*)sm;  // 128 q-rows x 128 m-cols, 16B-chunk XOR swizzle per row
#pragma unroll
  for (int mi = 0; mi < 4; ++mi) {
    const int qL = wr * 64 + mi * 16 + lrow;
    const int qG = n0 + qL;
#pragma unroll
    for (int ni = 0; ni < 4; ++ni) {
      const int tc = wc * 16 + ni * 4 + quad;      // true chunk (4 f32)
      const int stv = tc ^ (qL & 31);              // stored chunk
      f32x4 dv;
#pragma unroll
      for (int r = 0; r < 4; ++r) {
        const int mG = m0 + wc * 64 + ni * 16 + quad * 4 + r;
        float d = fmaf(-2.f, acc[mi][ni][r], sqq_[mi] + sqm_[ni][r]);
        if (mG == qG) d = 3.402823466e38f;
        dv[r] = d;
      }
      *(f32x4*)(smf + qL * 128 + stv * 4) = dv;
    }
  }
  __syncthreads();

  // selection: wave wid owns q rows [wid*32, wid*32+32); 2 lanes/row, 64 values/lane.
  // 4 independent 16-elem chains (read LDS, consume, discard - nothing kept in regs).
  const int qsel = wid * 32 + (lane & 31);
  const int half = lane >> 5;
  float kA[9], kB[9], kC[9], kD[9];
#pragma unroll
  for (int k = 0; k < 9; ++k) kA[k] = kB[k] = kC[k] = kD[k] = 3.402823466e38f;

  auto ins16 = [&](float* key, int tcb) {
#pragma unroll
    for (int i = 0; i < 4; ++i) {
      const int tc = tcb + i;
      const int stv = tc ^ (qsel & 31);
      f32x4 q4 = *(const f32x4*)(smf + qsel * 128 + stv * 4);
#pragma unroll
      for (int e = 0; e < 4; ++e) {
        key[8] = fminf(key[8], q4[e]);
#pragma unroll
        for (int s = 8; s >= 1; --s) ce2f(key[s - 1], key[s]);
      }
    }
  };
  ins16(kA, half * 16 + 0);
  ins16(kB, half * 16 + 4);
  ins16(kC, half * 16 + 8);
  ins16(kD, half * 16 + 12);
  mrg9(kA, kB);
  mrg9(kC, kD);
  mrg9(kA, kC);
  {  // merge the two half-lists across lanes (bitonic trick + 13-CE cleanup)
    float pk[9];
#pragma unroll
    for (int k = 0; k < 9; ++k) pk[k] = __shfl_xor(kA[k], 32, 64);
    float m[9];
#pragma unroll
    for (int k = 0; k < 9; ++k) m[k] = fminf(kA[k], pk[8 - k]);
    ce2f(m[0], m[8]);
    ce2f(m[1], m[5]); ce2f(m[2], m[6]); ce2f(m[3], m[7]); ce2f(m[4], m[8]);
    ce2f(m[1], m[3]); ce2f(m[2], m[4]); ce2f(m[5], m[7]); ce2f(m[6], m[8]);
    ce2f(m[1], m[2]); ce2f(m[3], m[4]); ce2f(m[5], m[6]); ce2f(m[7], m[8]);
#pragma unroll
    for (int k = 0; k < 9; ++k) kA[k] = m[k];
  }
  const float v9 = kA[8];
  int c_lt = 0;
#pragma unroll
  for (int k = 0; k < 8; ++k) c_lt += (kA[k] < v9) ? 1 : 0;

  // mask pass: re-read the 16 chunks from LDS (cheaper than 64 VGPRs of kept values)
  u64 lt_mask = 0ull, eq_mask = 0ull;
#pragma unroll
  for (int i = 0; i < 16; ++i) {
    const int tc = half * 16 + i;
    const int stv = tc ^ (qsel & 31);
    f32x4 q4 = *(const f32x4*)(smf + qsel * 128 + stv * 4);
#pragma unroll
    for (int e = 0; e < 4; ++e) {
      const int j = i * 4 + e;
      lt_mask |= (q4[e] < v9) ? (1ull << j) : 0ull;
      eq_mask |= (q4[e] == v9) ? (1ull << j) : 0ull;
    }
  }
  const int ltc = __popcll(lt_mask), eqc = __popcll(eq_mask);
  const int packed = ltc | (eqc << 16);
  const int other = __shfl_xor(packed, 32, 64);
  const int lt_pref = half ? (other & 0xFFFF) : 0;
  const int eq_pref = half ? (other >> 16) : 0;

  // part layout: [(b_local*8 + mt)][node] -> k_mrg reads coalesce
  u64* pp = part + (((size_t)(b_local * 8 + mt) * N_) + (n0 + qsel)) * 9;
  int slot = lt_pref;
  u64 msk = lt_mask;
  while (msk) {
    const int j = __builtin_ctzll(msk);
    msk &= msk - 1;
    const int mL = half * 64 + j;
    const int stv = (mL >> 2) ^ (qsel & 31);
    const float val = smf[qsel * 128 + stv * 4 + (mL & 3)];  // runtime idx -> LDS re-read
    unsigned fb = __float_as_uint(val);
    unsigned mono = (fb >> 31) ? ~fb : (fb | 0x80000000u);
    pp[slot++] = ((u64)mono << 32) | (unsigned)(m0 + mL);
  }
  unsigned fb9 = __float_as_uint(v9);
  unsigned mono9 = (fb9 >> 31) ? ~fb9 : (fb9 | 0x80000000u);
  slot = c_lt + eq_pref;
  msk = eq_mask;
  while (msk && slot < 9) {
    const int j = __builtin_ctzll(msk);
    msk &= msk - 1;
    pp[slot++] = ((u64)mono9 << 32) | (unsigned)(m0 + half * 64 + j);
  }
}

// ---------------- merge 8 per-segment top-9s per node -> nbr (coalesced) ----------------
__global__ void k_mrg(const u64* __restrict__ part, int* __restrict__ nbr, int base_node) {
  const int nl = blockIdx.x * 256 + threadIdx.x;
  const int bl = nl >> 10, q = nl & 1023;
  const u64* p = part + ((size_t)(bl * 8) * N_ + q) * 9;
  u64 key[9];
#pragma unroll
  for (int k = 0; k < 9; ++k) key[k] = ~0ull;
#pragma unroll
  for (int seg = 0; seg < 8; ++seg) {
    const u64* ps = p + (size_t)seg * N_ * 9;
#pragma unroll
    for (int k9 = 0; k9 < 9; ++k9) {
      u64 kk = ps[k9];
      key[8] = key[8] < kk ? key[8] : kk;
#pragma unroll
      for (int s = 8; s >= 1; --s) ce9u(key[s - 1], key[s]);
    }
  }
  int* np = nbr + (size_t)(base_node + nl) * K_;
#pragma unroll
  for (int k = 0; k < 9; ++k) np[k] = (int)(unsigned)(key[k] & 0xFFFFFFFFu);
}

// ---------------- MFMA xw[b][co][n]: A=Wg(h/l), B=xT(h/l), dbuf staging ----------------
__global__ __launch_bounds__(256, 3) void k_xw(const ushort* __restrict__ xhT,
                                               const ushort* __restrict__ xlT,
                                               const ushort* __restrict__ WgH,
                                               const ushort* __restrict__ WgL,
                                               float* __restrict__ xw) {
  const int bid = blockIdx.x;
  const int xcd = bid & 7, j = bid >> 3;   // 96 blocks per XCD
  const int pair = xcd * 16 + j / 6;       // (b,nt) pair; 6 consecutive j share it
  const int ct = j % 6;
  const int b = pair >> 3, nt = pair & 7;
  const int co0 = ct * 64, n0 = nt * 128;
  __shared__ alignas(16) char sm[2][24576];  // per buf: Ah@0 Al@4096 Bh@8192 Bl@16384
  const int t = threadIdx.x;
  const int lane = t & 63, wid = t >> 6, quad = lane >> 4, lrow = lane & 15;
  const int wr = wid >> 1, wc = wid & 1;
  const int lrow4 = lane >> 2, lpos = lane & 3;

  f32x4 acc[2][4];
#pragma unroll
  for (int mi = 0; mi < 2; ++mi)
#pragma unroll
    for (int ni = 0; ni < 4; ++ni) acc[mi][ni] = (f32x4){0.f, 0.f, 0.f, 0.f};

  const char* asrc[2] = {(const char*)(WgH + (size_t)co0 * C_),
                         (const char*)(WgL + (size_t)co0 * C_)};
  const char* bsrc[2] = {(const char*)(xhT + (size_t)(b * N_ + n0) * C_),
                         (const char*)(xlT + (size_t)(b * N_ + n0) * C_)};

  auto stage = [&](int it) {
    char* dst = sm[it & 1];
    const int ktB = it * 64;
#pragma unroll
    for (int i = 0; i < 6; ++i) {
      const int c = wid * 6 + i;
      const char* src;
      int base, row;
      if (c < 8) {
        const int arr = c >> 2, sub = c & 3;
        src = asrc[arr];
        base = arr * 4096 + sub * 1024;
        row = sub * 16 + lrow4;
      } else {
        const int cc = c - 8, arr = cc >> 3, sub = cc & 7;
        src = bsrc[arr];
        base = 8192 + arr * 8192 + sub * 1024;
        row = sub * 16 + lrow4;
      }
      const int swz = lpos ^ ((row >> 1) & 3);
      gld_lds16(src + (size_t)row * 768 + ktB + swz * 16, dst + base + lane * 16);
    }
  };

  stage(0);
  for (int it = 0; it < 12; ++it) {
    __syncthreads();
    if (it < 11) stage(it + 1);
    const char* smb = sm[it & 1];
    f16x8 bh[4], bl[4];
#pragma unroll
    for (int ni = 0; ni < 4; ++ni) {
      const int row = wr * 64 + ni * 16 + lrow;
      const int off = row * 64 + (quad ^ ((row >> 1) & 3)) * 16;
      bh[ni] = *(const f16x8*)(smb + 8192 + off);
      bl[ni] = *(const f16x8*)(smb + 16384 + off);
    }
#pragma unroll
    for (int mi = 0; mi < 2; ++mi) {
      const int row = wc * 32 + mi * 16 + lrow;
      const int off = row * 64 + (quad ^ ((row >> 1) & 3)) * 16;
      f16x8 ah = *(const f16x8*)(smb + off);
      f16x8 al = *(const f16x8*)(smb + 4096 + off);
#pragma unroll
      for (int ni = 0; ni < 4; ++ni) {
        acc[mi][ni] = __builtin_amdgcn_mfma_f32_16x16x32_f16(ah, bh[ni], acc[mi][ni], 0, 0, 0);
        acc[mi][ni] = __builtin_amdgcn_mfma_f32_16x16x32_f16(al, bh[ni], acc[mi][ni], 0, 0, 0);
        acc[mi][ni] = __builtin_amdgcn_mfma_f32_16x16x32_f16(ah, bl[ni], acc[mi][ni], 0, 0, 0);
      }
    }
  }
#pragma unroll
  for (int mi = 0; mi < 2; ++mi)
#pragma unroll
    for (int ni = 0; ni < 4; ++ni)
#pragma unroll
      for (int r = 0; r < 4; ++r) {
        const int c_g = co0 + wc * 32 + mi * 16 + quad * 4 + r;
        const int n_g = n0 + wr * 64 + ni * 16 + lrow;
        xw[((size_t)b * C_ + c_g) * N_ + n_g] = acc[mi][ni][r];
      }
}

// ---------------- aggregate (deg==10 uniformly) + BN partial stats ----------------
__global__ __launch_bounds__(256) void k_agg(const float* __restrict__ xw,
                                             const int* __restrict__ nbr,
                                             const float* __restrict__ bg,
                                             float* __restrict__ out,
                                             float* __restrict__ stats) {
  const int ct = blockIdx.x % (C_ / 8);  // 48
  const int b = blockIdx.x / (C_ / 8);
  const int c0 = ct * 8;
  __shared__ alignas(16) int nb_l[N_ * K_];       // 36864 B
  __shared__ alignas(16) float row_l[8][N_ + 4];  // 32896 B
  __shared__ float red[2][8][4];
  const int tid = threadIdx.x;
  const int4* gp = (const int4*)(nbr + (size_t)b * N_ * K_);
  int4* lp = (int4*)nb_l;
  for (int t = tid; t < N_ * K_ / 4; t += 256) lp[t] = gp[t];
  for (int t = tid; t < 8 * (N_ / 4); t += 256) {
    const int j = t >> 8, n4 = t & 255;  // N_/4 = 256
    float4 v = ((const float4*)(xw + ((size_t)(b * C_ + c0 + j)) * N_))[n4];
    *(float4*)&row_l[j][n4 * 4] = v;
  }
  __syncthreads();
  float bgc[8];
#pragma unroll
  for (int j = 0; j < 8; ++j) bgc[j] = bg[c0 + j];
  float s1[8], s2[8];
#pragma unroll
  for (int j = 0; j < 8; ++j) {
    s1[j] = 0.f;
    s2[j] = 0.f;
  }
  float* outb = out + ((size_t)b * C_ + c0) * N_;
#pragma unroll
  for (int s = 0; s < 4; ++s) {
    const int n = tid + 256 * s;
    const int* nn_ = &nb_l[n * K_];
    int idx[K_];
#pragma unroll
    for (int k = 0; k < K_; ++k) idx[k] = nn_[k];
    float a[8];
#pragma unroll
    for (int j = 0; j < 8; ++j) a[j] = row_l[j][n];
#pragma unroll
    for (int k = 0; k < K_; ++k) {
      const int m = idx[k];
#pragma unroll
      for (int j = 0; j < 8; ++j) a[j] += row_l[j][m];
    }
#pragma unroll
    for (int j = 0; j < 8; ++j) {
      float y = fmaf(a[j], 0.099999994f, bgc[j]);
      outb[(size_t)j * N_ + n] = y;
      s1[j] += y;
      s2[j] = fmaf(y, y, s2[j]);
    }
  }
#pragma unroll
  for (int off = 32; off > 0; off >>= 1)
#pragma unroll
    for (int j = 0; j < 8; ++j) {
      s1[j] += __shfl_down(s1[j], off, 64);
      s2[j] += __shfl_down(s2[j], off, 64);
    }
  const int lane = tid & 63, wid = tid >> 6;
  if (lane == 0)
#pragma unroll
    for (int j = 0; j < 8; ++j) {
      red[0][j][wid] = s1[j];
      red[1][j][wid] = s2[j];
    }
  __syncthreads();
  if (tid < 16) {
    const int j = tid & 7, which = tid >> 3;
    float v = red[which][j][0] + red[which][j][1] + red[which][j][2] + red[which][j][3];
    atomicAdd(&stats[which * C_ + c0 + j], v);
  }
}

// ---------------- BN (batch stats) + tanh-GELU + residual ----------------
__global__ void k_bn(const float* __restrict__ x, const float* __restrict__ gamma,
                     const float* __restrict__ beta, const float* __restrict__ stats,
                     float* __restrict__ out) {
  const int f = blockIdx.x * blockDim.x + threadIdx.x;
  const int e = f * 4;
  const int c = (e >> 10) % C_;
  const float inv = 1.f / 16384.f;
  const float mu = stats[c] * inv;
  const float var = fmaf(-mu, mu, stats[C_ + c] * inv);
  const float sc = gamma[c] * rsqrtf(var + 1e-5f);
  const float sh = fmaf(-mu, sc, beta[c]);
  float4 y = ((const float4*)out)[f];
  float4 xv = ((const float4*)x)[f];
  auto gl = [](float z) {
    float z3 = z * z * z;
    float t = 0.7978845608028654f * fmaf(0.044715f, z3, z);
    float th = tanhf(t);
    return 0.5f * z * (1.f + th);
  };
  float4 o;
  o.x = gl(fmaf(y.x, sc, sh)) + xv.x;
  o.y = gl(fmaf(y.y, sc, sh)) + xv.y;
  o.z = gl(fmaf(y.z, sc, sh)) + xv.z;
  o.w = gl(fmaf(y.w, sc, sh)) + xv.w;
  ((float4*)out)[f] = o;
}

extern "C" void kernel_launch(void* const* d_in, const int* in_sizes, int n_in,
                              void* d_out, int out_size, void* d_ws, size_t ws_size,
                              hipStream_t stream) {
  const float* x = (const float*)d_in[0];
  const float* Wg = (const float*)d_in[1];
  const float* bg = (const float*)d_in[2];
  const float* gamma = (const float*)d_in[3];
  const float* beta = (const float*)d_in[4];
  float* out = (float*)d_out;

  const int nb = 16;

  char* ws = (char*)d_ws;
  ushort* xhT = (ushort*)ws;                  // @0          12,582,912
  ushort* xlT = (ushort*)(ws + 12582912);     //             12,582,912
  ushort* WgH = (ushort*)(ws + 25165824);     //                294,912
  ushort* WgL = (ushort*)(ws + 25460736);     //                294,912
  float* sq = (float*)(ws + 25755648);        //                 65,536
  u64* part = (u64*)(ws + 25821184);          // nb*589,824 (9.4 MB)
  float* xw = (float*)(ws + 25821184);        // overlays part (part dead after k_mrg)
  size_t dreg = 25165824;                     // xw needs 25.17 MB
  int* nbr = (int*)(ws + 25821184 + dreg);    //                589,824
  float* stats = (float*)(ws + 25821184 + dreg + 589824);  //     3,072

  k_cvt<<<656, 256, 0, stream>>>(x, Wg, xhT, xlT, sq, WgH, WgL, stats);
  k_gram<<<nb * 64, 256, 0, stream>>>(xhT, xlT, sq, part, 0, nb);
  k_mrg<<<64, 256, 0, stream>>>(part, nbr, 0);
  k_xw<<<768, 256, 0, stream>>>(xhT, xlT, WgH, WgL, xw);
  k_agg<<<B_ * (C_ / 8), 256, 0, stream>>>(xw, nbr, bg, out, stats);
  k_bn<<<6144, 256, 0, stream>>>(x, gamma, beta, stats, out);
}

// Round 9
// 214.314 us; speedup vs baseline: 1.0341x; 1.0287x over previous
//
#include <hip/hip_runtime.h>
#include <math.h>

#define B_ 16
#define C_ 384
#define N_ 1024
#define K_ 9

typedef _Float16 f16x8 __attribute__((ext_vector_type(8)));
typedef _Float16 f16x4 __attribute__((ext_vector_type(4)));
typedef float f32x4 __attribute__((ext_vector_type(4)));
typedef unsigned long long u64;

__device__ __forceinline__ void gld_lds16(const void* g, void* l) {
  __builtin_amdgcn_global_load_lds((const __attribute__((address_space(1))) void*)g,
                                   (__attribute__((address_space(3))) void*)l, 16, 0, 0);
}

// ---------------- fused front-end: transpose+fp16 split + sq + Wg split + stats0 -------
__global__ __launch_bounds__(256) void k_cvt(const float* __restrict__ x,
                                             const float* __restrict__ Wg,
                                             ushort* __restrict__ xhT, ushort* __restrict__ xlT,
                                             float* __restrict__ sq, ushort* __restrict__ WgH,
                                             ushort* __restrict__ WgL,
                                             float* __restrict__ stats) {
  const int bid = blockIdx.x;
  const int t = threadIdx.x;
  if (bid >= 512) {  // ---- Wg split (144 blocks) + stats zero ----
    const int i = ((bid - 512) * 256 + t) * 4;
    float4 v = *(const float4*)(Wg + i);
    float vv[4] = {v.x, v.y, v.z, v.w};
    f16x4 hv, lv;
#pragma unroll
    for (int j = 0; j < 4; ++j) {
      _Float16 h = (_Float16)vv[j];
      hv[j] = h;
      lv[j] = (_Float16)(vv[j] - (float)h);
    }
    *(f16x4*)(WgH + i) = hv;
    *(f16x4*)(WgL + i) = lv;
    if (bid == 512) {
      stats[t] = 0.f;
      stats[t + 256] = 0.f;
      stats[t + 512] = 0.f;
    }
    return;
  }
  const int b = bid >> 5, n0 = (bid & 31) * 32;
  __shared__ float ld[384 * 33];  // 50688 B; bank(c*33+n) = (c+n)%32
  {
    const int cb = t >> 2, j8 = (t & 3) * 8;
#pragma unroll
    for (int i = 0; i < 6; ++i) {
      const int c = i * 64 + cb;
      const float* src = x + ((size_t)(b * C_ + c) * N_ + n0 + j8);
      float4 v0 = *(const float4*)src;
      float4 v1 = *(const float4*)(src + 4);
      float* dst = &ld[c * 33 + j8];
      dst[0] = v0.x; dst[1] = v0.y; dst[2] = v0.z; dst[3] = v0.w;
      dst[4] = v1.x; dst[5] = v1.y; dst[6] = v1.z; dst[7] = v1.w;
    }
  }
  __syncthreads();
  {
    const int n = t >> 3, l = t & 7;
#pragma unroll
    for (int i = 0; i < 6; ++i) {
      const int c8 = i * 64 + l * 8;
      f16x8 hv, lv;
#pragma unroll
      for (int j = 0; j < 8; ++j) {
        float v = ld[(c8 + j) * 33 + n];
        _Float16 h = (_Float16)v;
        hv[j] = h;
        lv[j] = (_Float16)(v - (float)h);
      }
      const size_t off = (size_t)(b * N_ + n0 + n) * C_ + c8;
      *(f16x8*)(xhT + off) = hv;
      *(f16x8*)(xlT + off) = lv;
    }
    double s = 0.0;
    const int cbase = l * 48;
#pragma unroll
    for (int cc = 0; cc < 48; ++cc) {
      float v = ld[(cbase + cc) * 33 + n];
      s = fma((double)v, (double)v, s);
    }
    s += __shfl_xor(s, 1, 64);
    s += __shfl_xor(s, 2, 64);
    s += __shfl_xor(s, 4, 64);
    if (l == 0) sq[b * N_ + n0 + n] = (float)s;
  }
}

__device__ __forceinline__ void ce2f(float& a, float& b) {
  float lo = fminf(a, b), hi = fmaxf(a, b);
  a = lo;
  b = hi;
}
__device__ __forceinline__ void ce9u(u64& a, u64& b) {
  u64 lo = a < b ? a : b;
  u64 hi = a < b ? b : a;
  a = lo;
  b = hi;
}
__device__ __forceinline__ void mrg9(float* a, const float* b) {
  float m[9];
#pragma unroll
  for (int k = 0; k < 9; ++k) m[k] = fminf(a[k], b[8 - k]);
  ce2f(m[0], m[8]);
  ce2f(m[1], m[5]); ce2f(m[2], m[6]); ce2f(m[3], m[7]); ce2f(m[4], m[8]);
  ce2f(m[1], m[3]); ce2f(m[2], m[4]); ce2f(m[5], m[7]); ce2f(m[6], m[8]);
  ce2f(m[1], m[2]); ce2f(m[3], m[4]); ce2f(m[5], m[6]); ce2f(m[7], m[8]);
#pragma unroll
  for (int k = 0; k < 9; ++k) a[k] = m[k];
}

// ---------------- fused dispatch: triangular Gram+top9 blocks || xw GEMM blocks -------
// blocks 0..575: Gram, 36 upper-triangular tiles/batch (rt<=mt). The LDS D-tile serves
// BOTH views: q-rows -> seg mt (as before) and, for off-diag tiles, m-cols -> seg rt
// (column reads are conflict-free under the XOR chunk swizzle: bank = 4*((m>>2)^(q&7))
// + (m&3), bijective over 32 lanes). Coverage seg t>=s via q-view of (s,t), t<s via
// m-view of (t,s): complete, unique, bitwise-identical distances (products commute,
// same mfma reduction tree). GEMM work -44%; selection work unchanged.
// blocks 576..1343: k_xw verbatim (independent work -> fills gram's tail slots and
// decorrelates barrier rhythms).
__global__ __launch_bounds__(256, 2) void k_gx(const ushort* __restrict__ xhT,
                                               const ushort* __restrict__ xlT,
                                               const float* __restrict__ sq,
                                               u64* __restrict__ part,
                                               const ushort* __restrict__ WgH,
                                               const ushort* __restrict__ WgL,
                                               float* __restrict__ xw) {
  __shared__ alignas(16) char sm[2][32768];
  const int bid = blockIdx.x;
  const int t = threadIdx.x;
  const int lane = t & 63, wid = t >> 6, quad = lane >> 4, lrow = lane & 15;
  const int wr = wid >> 1, wc = wid & 1;
  const int lrow4 = lane >> 2, lpos = lane & 3;

  if (bid >= 576) {  // ================= xw path =================
    const int bid2 = bid - 576;
    const int xcd = bid2 & 7, j = bid2 >> 3;
    const int pair = xcd * 16 + j / 6;
    const int ct = j % 6;
    const int b = pair >> 3, nt = pair & 7;
    const int co0 = ct * 64, n0 = nt * 128;
    char* smbase = &sm[0][0];  // uses 2 x 24576 of the 64KB

    f32x4 acc[2][4];
#pragma unroll
    for (int mi = 0; mi < 2; ++mi)
#pragma unroll
      for (int ni = 0; ni < 4; ++ni) acc[mi][ni] = (f32x4){0.f, 0.f, 0.f, 0.f};

    const char* asrc[2] = {(const char*)(WgH + (size_t)co0 * C_),
                           (const char*)(WgL + (size_t)co0 * C_)};
    const char* bsrc[2] = {(const char*)(xhT + (size_t)(b * N_ + n0) * C_),
                           (const char*)(xlT + (size_t)(b * N_ + n0) * C_)};

    auto stage = [&](int it) {
      char* dst = smbase + (it & 1) * 24576;
      const int ktB = it * 64;
#pragma unroll
      for (int i = 0; i < 6; ++i) {
        const int c = wid * 6 + i;
        const char* src;
        int base, row;
        if (c < 8) {
          const int arr = c >> 2, sub = c & 3;
          src = asrc[arr];
          base = arr * 4096 + sub * 1024;
          row = sub * 16 + lrow4;
        } else {
          const int cc = c - 8, arr = cc >> 3, sub = cc & 7;
          src = bsrc[arr];
          base = 8192 + arr * 8192 + sub * 1024;
          row = sub * 16 + lrow4;
        }
        const int swz = lpos ^ ((row >> 1) & 3);
        gld_lds16(src + (size_t)row * 768 + ktB + swz * 16, dst + base + lane * 16);
      }
    };

    stage(0);
    for (int it = 0; it < 12; ++it) {
      __syncthreads();
      if (it < 11) stage(it + 1);
      const char* smb = smbase + (it & 1) * 24576;
      f16x8 bh[4], bl[4];
#pragma unroll
      for (int ni = 0; ni < 4; ++ni) {
        const int row = wr * 64 + ni * 16 + lrow;
        const int off = row * 64 + (quad ^ ((row >> 1) & 3)) * 16;
        bh[ni] = *(const f16x8*)(smb + 8192 + off);
        bl[ni] = *(const f16x8*)(smb + 16384 + off);
      }
#pragma unroll
      for (int mi = 0; mi < 2; ++mi) {
        const int row = wc * 32 + mi * 16 + lrow;
        const int off = row * 64 + (quad ^ ((row >> 1) & 3)) * 16;
        f16x8 ah = *(const f16x8*)(smb + off);
        f16x8 al = *(const f16x8*)(smb + 4096 + off);
#pragma unroll
        for (int ni = 0; ni < 4; ++ni) {
          acc[mi][ni] = __builtin_amdgcn_mfma_f32_16x16x32_f16(ah, bh[ni], acc[mi][ni], 0, 0, 0);
          acc[mi][ni] = __builtin_amdgcn_mfma_f32_16x16x32_f16(al, bh[ni], acc[mi][ni], 0, 0, 0);
          acc[mi][ni] = __builtin_amdgcn_mfma_f32_16x16x32_f16(ah, bl[ni], acc[mi][ni], 0, 0, 0);
        }
      }
    }
#pragma unroll
    for (int mi = 0; mi < 2; ++mi)
#pragma unroll
      for (int ni = 0; ni < 4; ++ni)
#pragma unroll
        for (int r = 0; r < 4; ++r) {
          const int c_g = co0 + wc * 32 + mi * 16 + quad * 4 + r;
          const int n_g = n0 + wr * 64 + ni * 16 + lrow;
          xw[((size_t)b * C_ + c_g) * N_ + n_g] = acc[mi][ni][r];
        }
    return;
  }

  // ================= gram path (triangular) =================
  const int xcd = bid & 7, j = bid >> 3;  // j in 0..71
  const int b_local = xcd * 2 + j / 36;
  int pid = j % 36;
  int rt = 0, off0 = 0;
  while (pid >= off0 + (8 - rt)) {
    off0 += 8 - rt;
    ++rt;
  }
  const int mt = rt + (pid - off0);
  const int b = b_local;
  const int n0 = rt * 128, m0 = mt * 128;

  const char* src = (const char*)((wid & 1) ? xlT : xhT) +
                    (size_t)(b * N_ + ((wid >> 1) ? m0 : n0)) * C_ * 2;

  f32x4 acc[4][4];
#pragma unroll
  for (int mi = 0; mi < 4; ++mi)
#pragma unroll
    for (int ni = 0; ni < 4; ++ni) acc[mi][ni] = (f32x4){0.f, 0.f, 0.f, 0.f};

  auto stage = [&](int it) {
    char* dst = sm[it & 1] + wid * 8192;
    const int ktB = it * 64;
#pragma unroll
    for (int i = 0; i < 8; ++i) {
      const int row = i * 16 + lrow4;
      const int swz = lpos ^ ((row >> 1) & 3);
      gld_lds16(src + (size_t)row * 768 + ktB + swz * 16, dst + i * 1024 + lane * 16);
    }
  };

  stage(0);
  for (int it = 0; it < 12; ++it) {
    __syncthreads();
    if (it < 11) stage(it + 1);
    const char* smb = sm[it & 1];
    f16x8 ah[4], al[4];
#pragma unroll
    for (int mi = 0; mi < 4; ++mi) {
      const int row = wr * 64 + mi * 16 + lrow;
      const int off = row * 64 + (quad ^ ((row >> 1) & 3)) * 16;
      ah[mi] = *(const f16x8*)(smb + off);
      al[mi] = *(const f16x8*)(smb + 8192 + off);
    }
#pragma unroll
    for (int ni = 0; ni < 4; ++ni) {
      const int row = wc * 64 + ni * 16 + lrow;
      const int off = row * 64 + (quad ^ ((row >> 1) & 3)) * 16;
      f16x8 bh = *(const f16x8*)(smb + 16384 + off);
      f16x8 bl = *(const f16x8*)(smb + 24576 + off);
#pragma unroll
      for (int mi = 0; mi < 4; ++mi) {
        acc[mi][ni] = __builtin_amdgcn_mfma_f32_16x16x32_f16(bh, ah[mi], acc[mi][ni], 0, 0, 0);
        acc[mi][ni] = __builtin_amdgcn_mfma_f32_16x16x32_f16(bh, al[mi], acc[mi][ni], 0, 0, 0);
        acc[mi][ni] = __builtin_amdgcn_mfma_f32_16x16x32_f16(bl, ah[mi], acc[mi][ni], 0, 0, 0);
      }
    }
  }
  __syncthreads();

  const float* sqb = sq + b * N_;
  float sqm_[4][4];
#pragma unroll
  for (int ni = 0; ni < 4; ++ni)
#pragma unroll
    for (int r = 0; r < 4; ++r) sqm_[ni][r] = sqb[m0 + wc * 64 + ni * 16 + quad * 4 + r];
  float sqq_[4];
#pragma unroll
  for (int mi = 0; mi < 4; ++mi) sqq_[mi] = sqb[n0 + wr * 64 + mi * 16 + lrow];

  float* smf = (float*)sm;
#pragma unroll
  for (int mi = 0; mi < 4; ++mi) {
    const int qL = wr * 64 + mi * 16 + lrow;
    const int qG = n0 + qL;
#pragma unroll
    for (int ni = 0; ni < 4; ++ni) {
      const int tc = wc * 16 + ni * 4 + quad;
      const int stv = tc ^ (qL & 31);
      f32x4 dv;
#pragma unroll
      for (int r = 0; r < 4; ++r) {
        const int mG = m0 + wc * 64 + ni * 16 + quad * 4 + r;
        float d = fmaf(-2.f, acc[mi][ni][r], sqq_[mi] + sqm_[ni][r]);
        if (mG == qG) d = 3.402823466e38f;
        dv[r] = d;
      }
      *(f32x4*)(smf + qL * 128 + stv * 4) = dv;
    }
  }
  __syncthreads();

  const int half = lane >> 5;
  float kA[9], kB[9], kC[9], kD[9];

  // -------- q-view: row qsel over 128 m-cols -> part[seg mt][n0+qsel] --------
  {
    const int qsel = wid * 32 + (lane & 31);
#pragma unroll
    for (int k = 0; k < 9; ++k) kA[k] = kB[k] = kC[k] = kD[k] = 3.402823466e38f;
    auto ins16 = [&](float* key, int tcb) {
#pragma unroll
      for (int i = 0; i < 4; ++i) {
        const int tc = tcb + i;
        const int stv = tc ^ (qsel & 31);
        f32x4 q4 = *(const f32x4*)(smf + qsel * 128 + stv * 4);
#pragma unroll
        for (int e = 0; e < 4; ++e) {
          key[8] = fminf(key[8], q4[e]);
#pragma unroll
          for (int s = 8; s >= 1; --s) ce2f(key[s - 1], key[s]);
        }
      }
    };
    ins16(kA, half * 16 + 0);
    ins16(kB, half * 16 + 4);
    ins16(kC, half * 16 + 8);
    ins16(kD, half * 16 + 12);
    mrg9(kA, kB);
    mrg9(kC, kD);
    mrg9(kA, kC);
    {
      float pk[9];
#pragma unroll
      for (int k = 0; k < 9; ++k) pk[k] = __shfl_xor(kA[k], 32, 64);
      mrg9(kA, pk);
    }
    const float v9 = kA[8];
    int c_lt = 0;
#pragma unroll
    for (int k = 0; k < 8; ++k) c_lt += (kA[k] < v9) ? 1 : 0;

    u64 lt_mask = 0ull, eq_mask = 0ull;
#pragma unroll
    for (int i = 0; i < 16; ++i) {
      const int tc = half * 16 + i;
      const int stv = tc ^ (qsel & 31);
      f32x4 q4 = *(const f32x4*)(smf + qsel * 128 + stv * 4);
#pragma unroll
      for (int e = 0; e < 4; ++e) {
        const int jj = i * 4 + e;
        lt_mask |= (q4[e] < v9) ? (1ull << jj) : 0ull;
        eq_mask |= (q4[e] == v9) ? (1ull << jj) : 0ull;
      }
    }
    const int ltc = __popcll(lt_mask), eqc = __popcll(eq_mask);
    const int packed = ltc | (eqc << 16);
    const int other = __shfl_xor(packed, 32, 64);
    const int lt_pref = half ? (other & 0xFFFF) : 0;
    const int eq_pref = half ? (other >> 16) : 0;

    u64* pp = part + (((size_t)(b_local * 8 + mt) * N_) + (n0 + qsel)) * 9;
    int slot = lt_pref;
    u64 msk = lt_mask;
    while (msk) {
      const int jj = __builtin_ctzll(msk);
      msk &= msk - 1;
      const int mL = half * 64 + jj;
      const int stv = (mL >> 2) ^ (qsel & 31);
      const float val = smf[qsel * 128 + stv * 4 + (mL & 3)];
      unsigned fb = __float_as_uint(val);
      unsigned mono = (fb >> 31) ? ~fb : (fb | 0x80000000u);
      pp[slot++] = ((u64)mono << 32) | (unsigned)(m0 + mL);
    }
    unsigned fb9 = __float_as_uint(v9);
    unsigned mono9 = (fb9 >> 31) ? ~fb9 : (fb9 | 0x80000000u);
    slot = c_lt + eq_pref;
    msk = eq_mask;
    while (msk && slot < 9) {
      const int jj = __builtin_ctzll(msk);
      msk &= msk - 1;
      pp[slot++] = ((u64)mono9 << 32) | (unsigned)(m0 + half * 64 + jj);
    }
  }

  // -------- m-view (off-diag only): col msel over 128 q-rows -> part[seg rt][m0+msel] --
  if (rt != mt) {
    const int msel = wid * 32 + (lane & 31);
    const int mlo = msel & 3, mhi = msel >> 2;
#pragma unroll
    for (int k = 0; k < 9; ++k) kA[k] = kB[k] = kC[k] = kD[k] = 3.402823466e38f;
    auto insCol = [&](float* key, int q0) {
#pragma unroll
      for (int i = 0; i < 16; ++i) {
        const int qL = q0 + i;
        const float v = smf[qL * 128 + ((mhi ^ (qL & 31)) << 2) + mlo];
        key[8] = fminf(key[8], v);
#pragma unroll
        for (int s = 8; s >= 1; --s) ce2f(key[s - 1], key[s]);
      }
    };
    insCol(kA, half * 64 + 0);
    insCol(kB, half * 64 + 16);
    insCol(kC, half * 64 + 32);
    insCol(kD, half * 64 + 48);
    mrg9(kA, kB);
    mrg9(kC, kD);
    mrg9(kA, kC);
    {
      float pk[9];
#pragma unroll
      for (int k = 0; k < 9; ++k) pk[k] = __shfl_xor(kA[k], 32, 64);
      mrg9(kA, pk);
    }
    const float v9 = kA[8];
    int c_lt = 0;
#pragma unroll
    for (int k = 0; k < 8; ++k) c_lt += (kA[k] < v9) ? 1 : 0;

    u64 lt_mask = 0ull, eq_mask = 0ull;
#pragma unroll
    for (int jj = 0; jj < 64; ++jj) {
      const int qL = half * 64 + jj;
      const float v = smf[qL * 128 + ((mhi ^ (qL & 31)) << 2) + mlo];
      lt_mask |= (v < v9) ? (1ull << jj) : 0ull;
      eq_mask |= (v == v9) ? (1ull << jj) : 0ull;
    }
    const int ltc = __popcll(lt_mask), eqc = __popcll(eq_mask);
    const int packed = ltc | (eqc << 16);
    const int other = __shfl_xor(packed, 32, 64);
    const int lt_pref = half ? (other & 0xFFFF) : 0;
    const int eq_pref = half ? (other >> 16) : 0;

    u64* pp = part + (((size_t)(b_local * 8 + rt) * N_) + (m0 + msel)) * 9;
    int slot = lt_pref;
    u64 msk = lt_mask;
    while (msk) {
      const int jj = __builtin_ctzll(msk);
      msk &= msk - 1;
      const int qL = half * 64 + jj;
      const float val = smf[qL * 128 + ((mhi ^ (qL & 31)) << 2) + mlo];
      unsigned fb = __float_as_uint(val);
      unsigned mono = (fb >> 31) ? ~fb : (fb | 0x80000000u);
      pp[slot++] = ((u64)mono << 32) | (unsigned)(n0 + qL);
    }
    unsigned fb9 = __float_as_uint(v9);
    unsigned mono9 = (fb9 >> 31) ? ~fb9 : (fb9 | 0x80000000u);
    slot = c_lt + eq_pref;
    msk = eq_mask;
    while (msk && slot < 9) {
      const int jj = __builtin_ctzll(msk);
      msk &= msk - 1;
      pp[slot++] = ((u64)mono9 << 32) | (unsigned)(n0 + half * 64 + jj);
    }
  }
}

// ---------------- merge 8 per-segment top-9s per node -> nbr (coalesced) ----------------
__global__ void k_mrg(const u64* __restrict__ part, int* __restrict__ nbr, int base_node) {
  const int nl = blockIdx.x * 256 + threadIdx.x;
  const int bl = nl >> 10, q = nl & 1023;
  const u64* p = part + ((size_t)(bl * 8) * N_ + q) * 9;
  u64 key[9];
#pragma unroll
  for (int k = 0; k < 9; ++k) key[k] = ~0ull;
#pragma unroll
  for (int seg = 0; seg < 8; ++seg) {
    const u64* ps = p + (size_t)seg * N_ * 9;
#pragma unroll
    for (int k9 = 0; k9 < 9; ++k9) {
      u64 kk = ps[k9];
      key[8] = key[8] < kk ? key[8] : kk;
#pragma unroll
      for (int s = 8; s >= 1; --s) ce9u(key[s - 1], key[s]);
    }
  }
  int* np = nbr + (size_t)(base_node + nl) * K_;
#pragma unroll
  for (int k = 0; k < 9; ++k) np[k] = (int)(unsigned)(key[k] & 0xFFFFFFFFu);
}

// ---------------- aggregate (deg==10 uniformly) + BN partial stats ----------------
__global__ __launch_bounds__(256) void k_agg(const float* __restrict__ xw,
                                             const int* __restrict__ nbr,
                                             const float* __restrict__ bg,
                                             float* __restrict__ out,
                                             float* __restrict__ stats) {
  const int ct = blockIdx.x % (C_ / 8);  // 48
  const int b = blockIdx.x / (C_ / 8);
  const int c0 = ct * 8;
  __shared__ alignas(16) int nb_l[N_ * K_];       // 36864 B
  __shared__ alignas(16) float row_l[8][N_ + 4];  // 32896 B
  __shared__ float red[2][8][4];
  const int tid = threadIdx.x;
  const int4* gp = (const int4*)(nbr + (size_t)b * N_ * K_);
  int4* lp = (int4*)nb_l;
  for (int t = tid; t < N_ * K_ / 4; t += 256) lp[t] = gp[t];
  for (int t = tid; t < 8 * (N_ / 4); t += 256) {
    const int j = t >> 8, n4 = t & 255;
    float4 v = ((const float4*)(xw + ((size_t)(b * C_ + c0 + j)) * N_))[n4];
    *(float4*)&row_l[j][n4 * 4] = v;
  }
  __syncthreads();
  float bgc[8];
#pragma unroll
  for (int j = 0; j < 8; ++j) bgc[j] = bg[c0 + j];
  float s1[8], s2[8];
#pragma unroll
  for (int j = 0; j < 8; ++j) {
    s1[j] = 0.f;
    s2[j] = 0.f;
  }
  float* outb = out + ((size_t)b * C_ + c0) * N_;
#pragma unroll
  for (int s = 0; s < 4; ++s) {
    const int n = tid + 256 * s;
    const int* nn_ = &nb_l[n * K_];
    int idx[K_];
#pragma unroll
    for (int k = 0; k < K_; ++k) idx[k] = nn_[k];
    float a[8];
#pragma unroll
    for (int j = 0; j < 8; ++j) a[j] = row_l[j][n];
#pragma unroll
    for (int k = 0; k < K_; ++k) {
      const int m = idx[k];
#pragma unroll
      for (int j = 0; j < 8; ++j) a[j] += row_l[j][m];
    }
#pragma unroll
    for (int j = 0; j < 8; ++j) {
      float y = fmaf(a[j], 0.099999994f, bgc[j]);
      outb[(size_t)j * N_ + n] = y;
      s1[j] += y;
      s2[j] = fmaf(y, y, s2[j]);
    }
  }
#pragma unroll
  for (int off = 32; off > 0; off >>= 1)
#pragma unroll
    for (int j = 0; j < 8; ++j) {
      s1[j] += __shfl_down(s1[j], off, 64);
      s2[j] += __shfl_down(s2[j], off, 64);
    }
  const int lane = tid & 63, wid = tid >> 6;
  if (lane == 0)
#pragma unroll
    for (int j = 0; j < 8; ++j) {
      red[0][j][wid] = s1[j];
      red[1][j][wid] = s2[j];
    }
  __syncthreads();
  if (tid < 16) {
    const int j = tid & 7, which = tid >> 3;
    float v = red[which][j][0] + red[which][j][1] + red[which][j][2] + red[which][j][3];
    atomicAdd(&stats[which * C_ + c0 + j], v);
  }
}

// ---------------- BN (batch stats) + tanh-GELU + residual ----------------
__global__ void k_bn(const float* __restrict__ x, const float* __restrict__ gamma,
                     const float* __restrict__ beta, const float* __restrict__ stats,
                     float* __restrict__ out) {
  const int f = blockIdx.x * blockDim.x + threadIdx.x;
  const int e = f * 4;
  const int c = (e >> 10) % C_;
  const float inv = 1.f / 16384.f;
  const float mu = stats[c] * inv;
  const float var = fmaf(-mu, mu, stats[C_ + c] * inv);
  const float sc = gamma[c] * rsqrtf(var + 1e-5f);
  const float sh = fmaf(-mu, sc, beta[c]);
  float4 y = ((const float4*)out)[f];
  float4 xv = ((const float4*)x)[f];
  auto gl = [](float z) {
    float z3 = z * z * z;
    float t = 0.7978845608028654f * fmaf(0.044715f, z3, z);
    float th = tanhf(t);
    return 0.5f * z * (1.f + th);
  };
  float4 o;
  o.x = gl(fmaf(y.x, sc, sh)) + xv.x;
  o.y = gl(fmaf(y.y, sc, sh)) + xv.y;
  o.z = gl(fmaf(y.z, sc, sh)) + xv.z;
  o.w = gl(fmaf(y.w, sc, sh)) + xv.w;
  ((float4*)out)[f] = o;
}

extern "C" void kernel_launch(void* const* d_in, const int* in_sizes, int n_in,
                              void* d_out, int out_size, void* d_ws, size_t ws_size,
                              hipStream_t stream) {
  const float* x = (const float*)d_in[0];
  const float* Wg = (const float*)d_in[1];
  const float* bg = (const float*)d_in[2];
  const float* gamma = (const float*)d_in[3];
  const float* beta = (const float*)d_in[4];
  float* out = (float*)d_out;

  char* ws = (char*)d_ws;
  ushort* xhT = (ushort*)ws;                  // @0          12,582,912
  ushort* xlT = (ushort*)(ws + 12582912);     //             12,582,912
  ushort* WgH = (ushort*)(ws + 25165824);     //                294,912
  ushort* WgL = (ushort*)(ws + 25460736);     //                294,912
  float* sq = (float*)(ws + 25755648);        //                 65,536
  u64* part = (u64*)(ws + 25821184);          // 16*589,824 (9.4 MB)
  float* xw = (float*)(ws + 25821184);        // overlays part? NO: xw live with part in k_gx
  // k_gx writes BOTH part and xw concurrently -> they must not overlap.
  // layout: part @25,821,184 (9,437,184) ; xw @35,258,368 (25,165,824)
  part = (u64*)(ws + 25821184);
  xw = (float*)(ws + 25821184 + 9437184);
  int* nbr = (int*)(ws + 25821184 + 9437184 + 25165824);   //      589,824
  float* stats = (float*)(ws + 25821184 + 9437184 + 25165824 + 589824);  // 3,072

  k_cvt<<<656, 256, 0, stream>>>(x, Wg, xhT, xlT, sq, WgH, WgL, stats);
  k_gx<<<1344, 256, 0, stream>>>(xhT, xlT, sq, part, WgH, WgL, xw);
  k_mrg<<<64, 256, 0, stream>>>(part, nbr, 0);
  k_agg<<<B_ * (C_ / 8), 256, 0, stream>>>(xw, nbr, bg, out, stats);
  k_bn<<<6144, 256, 0, stream>>>(x, gamma, beta, stats, out);
}

// Round 10
// 213.897 us; speedup vs baseline: 1.0361x; 1.0020x over previous
//
#include <hip/hip_runtime.h>
#include <math.h>

#define B_ 16
#define C_ 384
#define N_ 1024
#define K_ 9

typedef _Float16 f16x8 __attribute__((ext_vector_type(8)));
typedef _Float16 f16x4 __attribute__((ext_vector_type(4)));
typedef float f32x4 __attribute__((ext_vector_type(4)));
typedef unsigned long long u64;

__device__ __forceinline__ void gld_lds16(const void* g, void* l) {
  __builtin_amdgcn_global_load_lds((const __attribute__((address_space(1))) void*)g,
                                   (__attribute__((address_space(3))) void*)l, 16, 0, 0);
}

// ---------------- fused front-end: transpose+fp16 split + sq + Wg split + stats0 -------
__global__ __launch_bounds__(256) void k_cvt(const float* __restrict__ x,
                                             const float* __restrict__ Wg,
                                             ushort* __restrict__ xhT, ushort* __restrict__ xlT,
                                             float* __restrict__ sq, ushort* __restrict__ WgH,
                                             ushort* __restrict__ WgL,
                                             float* __restrict__ stats) {
  const int bid = blockIdx.x;
  const int t = threadIdx.x;
  if (bid >= 512) {  // ---- Wg split (144 blocks) + stats zero ----
    const int i = ((bid - 512) * 256 + t) * 4;
    float4 v = *(const float4*)(Wg + i);
    float vv[4] = {v.x, v.y, v.z, v.w};
    f16x4 hv, lv;
#pragma unroll
    for (int j = 0; j < 4; ++j) {
      _Float16 h = (_Float16)vv[j];
      hv[j] = h;
      lv[j] = (_Float16)(vv[j] - (float)h);
    }
    *(f16x4*)(WgH + i) = hv;
    *(f16x4*)(WgL + i) = lv;
    if (bid == 512) {
      stats[t] = 0.f;
      stats[t + 256] = 0.f;
      stats[t + 512] = 0.f;
    }
    return;
  }
  const int b = bid >> 5, n0 = (bid & 31) * 32;
  __shared__ float ld[384 * 33];  // 50688 B; bank(c*33+n) = (c+n)%32
  {
    const int cb = t >> 2, j8 = (t & 3) * 8;
#pragma unroll
    for (int i = 0; i < 6; ++i) {
      const int c = i * 64 + cb;
      const float* src = x + ((size_t)(b * C_ + c) * N_ + n0 + j8);
      float4 v0 = *(const float4*)src;
      float4 v1 = *(const float4*)(src + 4);
      float* dst = &ld[c * 33 + j8];
      dst[0] = v0.x; dst[1] = v0.y; dst[2] = v0.z; dst[3] = v0.w;
      dst[4] = v1.x; dst[5] = v1.y; dst[6] = v1.z; dst[7] = v1.w;
    }
  }
  __syncthreads();
  {
    const int n = t >> 3, l = t & 7;
#pragma unroll
    for (int i = 0; i < 6; ++i) {
      const int c8 = i * 64 + l * 8;
      f16x8 hv, lv;
#pragma unroll
      for (int j = 0; j < 8; ++j) {
        float v = ld[(c8 + j) * 33 + n];
        _Float16 h = (_Float16)v;
        hv[j] = h;
        lv[j] = (_Float16)(v - (float)h);
      }
      const size_t off = (size_t)(b * N_ + n0 + n) * C_ + c8;
      *(f16x8*)(xhT + off) = hv;
      *(f16x8*)(xlT + off) = lv;
    }
    double s = 0.0;
    const int cbase = l * 48;
#pragma unroll
    for (int cc = 0; cc < 48; ++cc) {
      float v = ld[(cbase + cc) * 33 + n];
      s = fma((double)v, (double)v, s);
    }
    s += __shfl_xor(s, 1, 64);
    s += __shfl_xor(s, 2, 64);
    s += __shfl_xor(s, 4, 64);
    if (l == 0) sq[b * N_ + n0 + n] = (float)s;
  }
}

__device__ __forceinline__ void ce2f(float& a, float& b) {
  float lo = fminf(a, b), hi = fmaxf(a, b);
  a = lo;
  b = hi;
}
__device__ __forceinline__ void ce9u(u64& a, u64& b) {
  u64 lo = a < b ? a : b;
  u64 hi = a < b ? b : a;
  a = lo;
  b = hi;
}
__device__ __forceinline__ void mrg9(float* a, const float* b) {
  float m[9];
#pragma unroll
  for (int k = 0; k < 9; ++k) m[k] = fminf(a[k], b[8 - k]);
  ce2f(m[0], m[8]);
  ce2f(m[1], m[5]); ce2f(m[2], m[6]); ce2f(m[3], m[7]); ce2f(m[4], m[8]);
  ce2f(m[1], m[3]); ce2f(m[2], m[4]); ce2f(m[5], m[7]); ce2f(m[6], m[8]);
  ce2f(m[1], m[2]); ce2f(m[3], m[4]); ce2f(m[5], m[6]); ce2f(m[7], m[8]);
#pragma unroll
  for (int k = 0; k < 9; ++k) a[k] = m[k];
}

// ---------------- triangular MFMA Gram + dual-view top-9 (standalone, 576 blocks) ------
// R9 gram path un-fused: 36 upper-tri tiles/batch; q-view -> seg mt, m-view (off-diag)
// -> seg rt. pid map reordered: 28 off-diag tiles (2 views, expensive) FIRST, 8 diagonal
// tiles (1 view, cheap) LAST -> the 64-block straggler tail (576 = 1.125*512 resident)
// is populated by cheap blocks.
__global__ __launch_bounds__(256, 2) void k_gram(const ushort* __restrict__ xhT,
                                                 const ushort* __restrict__ xlT,
                                                 const float* __restrict__ sq,
                                                 u64* __restrict__ part) {
  __shared__ alignas(16) char sm[2][32768];
  const int bid = blockIdx.x;
  const int t = threadIdx.x;
  const int lane = t & 63, wid = t >> 6, quad = lane >> 4, lrow = lane & 15;
  const int wr = wid >> 1, wc = wid & 1;
  const int lrow4 = lane >> 2, lpos = lane & 3;

  const int xcd = bid & 7, j = bid >> 3;  // j in 0..71
  const int b_local = xcd * 2 + j / 36;
  const int pid = j % 36;
  int rt, mt;
  if (pid < 28) {  // off-diagonal tiles first
    int idx = pid, off0 = 0;
    rt = 0;
    while (idx >= off0 + (7 - rt)) {
      off0 += 7 - rt;
      ++rt;
    }
    mt = rt + 1 + (idx - off0);
  } else {  // diagonal tiles last (cheap: single view)
    rt = pid - 28;
    mt = rt;
  }
  const int b = b_local;
  const int n0 = rt * 128, m0 = mt * 128;

  const char* src = (const char*)((wid & 1) ? xlT : xhT) +
                    (size_t)(b * N_ + ((wid >> 1) ? m0 : n0)) * C_ * 2;

  f32x4 acc[4][4];
#pragma unroll
  for (int mi = 0; mi < 4; ++mi)
#pragma unroll
    for (int ni = 0; ni < 4; ++ni) acc[mi][ni] = (f32x4){0.f, 0.f, 0.f, 0.f};

  auto stage = [&](int it) {
    char* dst = sm[it & 1] + wid * 8192;
    const int ktB = it * 64;
#pragma unroll
    for (int i = 0; i < 8; ++i) {
      const int row = i * 16 + lrow4;
      const int swz = lpos ^ ((row >> 1) & 3);
      gld_lds16(src + (size_t)row * 768 + ktB + swz * 16, dst + i * 1024 + lane * 16);
    }
  };

  stage(0);
  for (int it = 0; it < 12; ++it) {
    __syncthreads();
    if (it < 11) stage(it + 1);
    const char* smb = sm[it & 1];
    f16x8 ah[4], al[4];
#pragma unroll
    for (int mi = 0; mi < 4; ++mi) {
      const int row = wr * 64 + mi * 16 + lrow;
      const int off = row * 64 + (quad ^ ((row >> 1) & 3)) * 16;
      ah[mi] = *(const f16x8*)(smb + off);
      al[mi] = *(const f16x8*)(smb + 8192 + off);
    }
#pragma unroll
    for (int ni = 0; ni < 4; ++ni) {
      const int row = wc * 64 + ni * 16 + lrow;
      const int off = row * 64 + (quad ^ ((row >> 1) & 3)) * 16;
      f16x8 bh = *(const f16x8*)(smb + 16384 + off);
      f16x8 bl = *(const f16x8*)(smb + 24576 + off);
#pragma unroll
      for (int mi = 0; mi < 4; ++mi) {
        acc[mi][ni] = __builtin_amdgcn_mfma_f32_16x16x32_f16(bh, ah[mi], acc[mi][ni], 0, 0, 0);
        acc[mi][ni] = __builtin_amdgcn_mfma_f32_16x16x32_f16(bh, al[mi], acc[mi][ni], 0, 0, 0);
        acc[mi][ni] = __builtin_amdgcn_mfma_f32_16x16x32_f16(bl, ah[mi], acc[mi][ni], 0, 0, 0);
      }
    }
  }
  __syncthreads();

  const float* sqb = sq + b * N_;
  float sqm_[4][4];
#pragma unroll
  for (int ni = 0; ni < 4; ++ni)
#pragma unroll
    for (int r = 0; r < 4; ++r) sqm_[ni][r] = sqb[m0 + wc * 64 + ni * 16 + quad * 4 + r];
  float sqq_[4];
#pragma unroll
  for (int mi = 0; mi < 4; ++mi) sqq_[mi] = sqb[n0 + wr * 64 + mi * 16 + lrow];

  float* smf = (float*)sm;
#pragma unroll
  for (int mi = 0; mi < 4; ++mi) {
    const int qL = wr * 64 + mi * 16 + lrow;
    const int qG = n0 + qL;
#pragma unroll
    for (int ni = 0; ni < 4; ++ni) {
      const int tc = wc * 16 + ni * 4 + quad;
      const int stv = tc ^ (qL & 31);
      f32x4 dv;
#pragma unroll
      for (int r = 0; r < 4; ++r) {
        const int mG = m0 + wc * 64 + ni * 16 + quad * 4 + r;
        float d = fmaf(-2.f, acc[mi][ni][r], sqq_[mi] + sqm_[ni][r]);
        if (mG == qG) d = 3.402823466e38f;
        dv[r] = d;
      }
      *(f32x4*)(smf + qL * 128 + stv * 4) = dv;
    }
  }
  __syncthreads();

  const int half = lane >> 5;
  float kA[9], kB[9], kC[9], kD[9];

  // -------- q-view: row qsel over 128 m-cols -> part[seg mt][n0+qsel] --------
  {
    const int qsel = wid * 32 + (lane & 31);
#pragma unroll
    for (int k = 0; k < 9; ++k) kA[k] = kB[k] = kC[k] = kD[k] = 3.402823466e38f;
    auto ins16 = [&](float* key, int tcb) {
#pragma unroll
      for (int i = 0; i < 4; ++i) {
        const int tc = tcb + i;
        const int stv = tc ^ (qsel & 31);
        f32x4 q4 = *(const f32x4*)(smf + qsel * 128 + stv * 4);
#pragma unroll
        for (int e = 0; e < 4; ++e) {
          key[8] = fminf(key[8], q4[e]);
#pragma unroll
          for (int s = 8; s >= 1; --s) ce2f(key[s - 1], key[s]);
        }
      }
    };
    ins16(kA, half * 16 + 0);
    ins16(kB, half * 16 + 4);
    ins16(kC, half * 16 + 8);
    ins16(kD, half * 16 + 12);
    mrg9(kA, kB);
    mrg9(kC, kD);
    mrg9(kA, kC);
    {
      float pk[9];
#pragma unroll
      for (int k = 0; k < 9; ++k) pk[k] = __shfl_xor(kA[k], 32, 64);
      mrg9(kA, pk);
    }
    const float v9 = kA[8];
    int c_lt = 0;
#pragma unroll
    for (int k = 0; k < 8; ++k) c_lt += (kA[k] < v9) ? 1 : 0;

    u64 lt_mask = 0ull, eq_mask = 0ull;
#pragma unroll
    for (int i = 0; i < 16; ++i) {
      const int tc = half * 16 + i;
      const int stv = tc ^ (qsel & 31);
      f32x4 q4 = *(const f32x4*)(smf + qsel * 128 + stv * 4);
#pragma unroll
      for (int e = 0; e < 4; ++e) {
        const int jj = i * 4 + e;
        lt_mask |= (q4[e] < v9) ? (1ull << jj) : 0ull;
        eq_mask |= (q4[e] == v9) ? (1ull << jj) : 0ull;
      }
    }
    const int ltc = __popcll(lt_mask), eqc = __popcll(eq_mask);
    const int packed = ltc | (eqc << 16);
    const int other = __shfl_xor(packed, 32, 64);
    const int lt_pref = half ? (other & 0xFFFF) : 0;
    const int eq_pref = half ? (other >> 16) : 0;

    u64* pp = part + (((size_t)(b_local * 8 + mt) * N_) + (n0 + qsel)) * 9;
    int slot = lt_pref;
    u64 msk = lt_mask;
    while (msk) {
      const int jj = __builtin_ctzll(msk);
      msk &= msk - 1;
      const int mL = half * 64 + jj;
      const int stv = (mL >> 2) ^ (qsel & 31);
      const float val = smf[qsel * 128 + stv * 4 + (mL & 3)];
      unsigned fb = __float_as_uint(val);
      unsigned mono = (fb >> 31) ? ~fb : (fb | 0x80000000u);
      pp[slot++] = ((u64)mono << 32) | (unsigned)(m0 + mL);
    }
    unsigned fb9 = __float_as_uint(v9);
    unsigned mono9 = (fb9 >> 31) ? ~fb9 : (fb9 | 0x80000000u);
    slot = c_lt + eq_pref;
    msk = eq_mask;
    while (msk && slot < 9) {
      const int jj = __builtin_ctzll(msk);
      msk &= msk - 1;
      pp[slot++] = ((u64)mono9 << 32) | (unsigned)(m0 + half * 64 + jj);
    }
  }

  // -------- m-view (off-diag only): col msel over 128 q-rows -> part[seg rt][m0+msel] --
  if (rt != mt) {
    const int msel = wid * 32 + (lane & 31);
    const int mlo = msel & 3, mhi = msel >> 2;
#pragma unroll
    for (int k = 0; k < 9; ++k) kA[k] = kB[k] = kC[k] = kD[k] = 3.402823466e38f;
    auto insCol = [&](float* key, int q0) {
#pragma unroll
      for (int i = 0; i < 16; ++i) {
        const int qL = q0 + i;
        const float v = smf[qL * 128 + ((mhi ^ (qL & 31)) << 2) + mlo];
        key[8] = fminf(key[8], v);
#pragma unroll
        for (int s = 8; s >= 1; --s) ce2f(key[s - 1], key[s]);
      }
    };
    insCol(kA, half * 64 + 0);
    insCol(kB, half * 64 + 16);
    insCol(kC, half * 64 + 32);
    insCol(kD, half * 64 + 48);
    mrg9(kA, kB);
    mrg9(kC, kD);
    mrg9(kA, kC);
    {
      float pk[9];
#pragma unroll
      for (int k = 0; k < 9; ++k) pk[k] = __shfl_xor(kA[k], 32, 64);
      mrg9(kA, pk);
    }
    const float v9 = kA[8];
    int c_lt = 0;
#pragma unroll
    for (int k = 0; k < 8; ++k) c_lt += (kA[k] < v9) ? 1 : 0;

    u64 lt_mask = 0ull, eq_mask = 0ull;
#pragma unroll
    for (int jj = 0; jj < 64; ++jj) {
      const int qL = half * 64 + jj;
      const float v = smf[qL * 128 + ((mhi ^ (qL & 31)) << 2) + mlo];
      lt_mask |= (v < v9) ? (1ull << jj) : 0ull;
      eq_mask |= (v == v9) ? (1ull << jj) : 0ull;
    }
    const int ltc = __popcll(lt_mask), eqc = __popcll(eq_mask);
    const int packed = ltc | (eqc << 16);
    const int other = __shfl_xor(packed, 32, 64);
    const int lt_pref = half ? (other & 0xFFFF) : 0;
    const int eq_pref = half ? (other >> 16) : 0;

    u64* pp = part + (((size_t)(b_local * 8 + rt) * N_) + (m0 + msel)) * 9;
    int slot = lt_pref;
    u64 msk = lt_mask;
    while (msk) {
      const int jj = __builtin_ctzll(msk);
      msk &= msk - 1;
      const int qL = half * 64 + jj;
      const float val = smf[qL * 128 + ((mhi ^ (qL & 31)) << 2) + mlo];
      unsigned fb = __float_as_uint(val);
      unsigned mono = (fb >> 31) ? ~fb : (fb | 0x80000000u);
      pp[slot++] = ((u64)mono << 32) | (unsigned)(n0 + qL);
    }
    unsigned fb9 = __float_as_uint(v9);
    unsigned mono9 = (fb9 >> 31) ? ~fb9 : (fb9 | 0x80000000u);
    slot = c_lt + eq_pref;
    msk = eq_mask;
    while (msk && slot < 9) {
      const int jj = __builtin_ctzll(msk);
      msk &= msk - 1;
      pp[slot++] = ((u64)mono9 << 32) | (unsigned)(n0 + half * 64 + jj);
    }
  }
}

// ---------------- MFMA xw[b][co][n] (standalone, 48KB LDS, 3 blocks/CU) ----------------
// 768 blocks at 3/CU = exactly one resident generation. XCD swizzle keeps the 6
// ct-blocks sharing one (b,nt) B-tile on one XCD's L2.
__global__ __launch_bounds__(256, 3) void k_xw(const ushort* __restrict__ xhT,
                                               const ushort* __restrict__ xlT,
                                               const ushort* __restrict__ WgH,
                                               const ushort* __restrict__ WgL,
                                               float* __restrict__ xw) {
  const int bid = blockIdx.x;
  const int xcd = bid & 7, j = bid >> 3;   // 96 blocks per XCD
  const int pair = xcd * 16 + j / 6;       // (b,nt) pair; 6 consecutive j share it
  const int ct = j % 6;
  const int b = pair >> 3, nt = pair & 7;
  const int co0 = ct * 64, n0 = nt * 128;
  __shared__ alignas(16) char sm[2][24576];  // per buf: Ah@0 Al@4096 Bh@8192 Bl@16384
  const int t = threadIdx.x;
  const int lane = t & 63, wid = t >> 6, quad = lane >> 4, lrow = lane & 15;
  const int wr = wid >> 1, wc = wid & 1;
  const int lrow4 = lane >> 2, lpos = lane & 3;

  f32x4 acc[2][4];
#pragma unroll
  for (int mi = 0; mi < 2; ++mi)
#pragma unroll
    for (int ni = 0; ni < 4; ++ni) acc[mi][ni] = (f32x4){0.f, 0.f, 0.f, 0.f};

  const char* asrc[2] = {(const char*)(WgH + (size_t)co0 * C_),
                         (const char*)(WgL + (size_t)co0 * C_)};
  const char* bsrc[2] = {(const char*)(xhT + (size_t)(b * N_ + n0) * C_),
                         (const char*)(xlT + (size_t)(b * N_ + n0) * C_)};

  auto stage = [&](int it) {
    char* dst = sm[it & 1];
    const int ktB = it * 64;
#pragma unroll
    for (int i = 0; i < 6; ++i) {
      const int c = wid * 6 + i;
      const char* src;
      int base, row;
      if (c < 8) {
        const int arr = c >> 2, sub = c & 3;
        src = asrc[arr];
        base = arr * 4096 + sub * 1024;
        row = sub * 16 + lrow4;
      } else {
        const int cc = c - 8, arr = cc >> 3, sub = cc & 7;
        src = bsrc[arr];
        base = 8192 + arr * 8192 + sub * 1024;
        row = sub * 16 + lrow4;
      }
      const int swz = lpos ^ ((row >> 1) & 3);
      gld_lds16(src + (size_t)row * 768 + ktB + swz * 16, dst + base + lane * 16);
    }
  };

  stage(0);
  for (int it = 0; it < 12; ++it) {
    __syncthreads();
    if (it < 11) stage(it + 1);
    const char* smb = sm[it & 1];
    f16x8 bh[4], bl[4];
#pragma unroll
    for (int ni = 0; ni < 4; ++ni) {
      const int row = wr * 64 + ni * 16 + lrow;
      const int off = row * 64 + (quad ^ ((row >> 1) & 3)) * 16;
      bh[ni] = *(const f16x8*)(smb + 8192 + off);
      bl[ni] = *(const f16x8*)(smb + 16384 + off);
    }
#pragma unroll
    for (int mi = 0; mi < 2; ++mi) {
      const int row = wc * 32 + mi * 16 + lrow;
      const int off = row * 64 + (quad ^ ((row >> 1) & 3)) * 16;
      f16x8 ah = *(const f16x8*)(smb + off);
      f16x8 al = *(const f16x8*)(smb + 4096 + off);
#pragma unroll
      for (int ni = 0; ni < 4; ++ni) {
        acc[mi][ni] = __builtin_amdgcn_mfma_f32_16x16x32_f16(ah, bh[ni], acc[mi][ni], 0, 0, 0);
        acc[mi][ni] = __builtin_amdgcn_mfma_f32_16x16x32_f16(al, bh[ni], acc[mi][ni], 0, 0, 0);
        acc[mi][ni] = __builtin_amdgcn_mfma_f32_16x16x32_f16(ah, bl[ni], acc[mi][ni], 0, 0, 0);
      }
    }
  }
#pragma unroll
  for (int mi = 0; mi < 2; ++mi)
#pragma unroll
    for (int ni = 0; ni < 4; ++ni)
#pragma unroll
      for (int r = 0; r < 4; ++r) {
        const int c_g = co0 + wc * 32 + mi * 16 + quad * 4 + r;
        const int n_g = n0 + wr * 64 + ni * 16 + lrow;
        xw[((size_t)b * C_ + c_g) * N_ + n_g] = acc[mi][ni][r];
      }
}

// ---------------- merge 8 per-segment top-9s per node -> nbr (coalesced) ----------------
__global__ void k_mrg(const u64* __restrict__ part, int* __restrict__ nbr, int base_node) {
  const int nl = blockIdx.x * 256 + threadIdx.x;
  const int bl = nl >> 10, q = nl & 1023;
  const u64* p = part + ((size_t)(bl * 8) * N_ + q) * 9;
  u64 key[9];
#pragma unroll
  for (int k = 0; k < 9; ++k) key[k] = ~0ull;
#pragma unroll
  for (int seg = 0; seg < 8; ++seg) {
    const u64* ps = p + (size_t)seg * N_ * 9;
#pragma unroll
    for (int k9 = 0; k9 < 9; ++k9) {
      u64 kk = ps[k9];
      key[8] = key[8] < kk ? key[8] : kk;
#pragma unroll
      for (int s = 8; s >= 1; --s) ce9u(key[s - 1], key[s]);
    }
  }
  int* np = nbr + (size_t)(base_node + nl) * K_;
#pragma unroll
  for (int k = 0; k < 9; ++k) np[k] = (int)(unsigned)(key[k] & 0xFFFFFFFFu);
}

// ---------------- aggregate (deg==10 uniformly) + BN partial stats ----------------
__global__ __launch_bounds__(256) void k_agg(const float* __restrict__ xw,
                                             const int* __restrict__ nbr,
                                             const float* __restrict__ bg,
                                             float* __restrict__ out,
                                             float* __restrict__ stats) {
  const int ct = blockIdx.x % (C_ / 8);  // 48
  const int b = blockIdx.x / (C_ / 8);
  const int c0 = ct * 8;
  __shared__ alignas(16) int nb_l[N_ * K_];       // 36864 B
  __shared__ alignas(16) float row_l[8][N_ + 4];  // 32896 B
  __shared__ float red[2][8][4];
  const int tid = threadIdx.x;
  const int4* gp = (const int4*)(nbr + (size_t)b * N_ * K_);
  int4* lp = (int4*)nb_l;
  for (int t = tid; t < N_ * K_ / 4; t += 256) lp[t] = gp[t];
  for (int t = tid; t < 8 * (N_ / 4); t += 256) {
    const int j = t >> 8, n4 = t & 255;
    float4 v = ((const float4*)(xw + ((size_t)(b * C_ + c0 + j)) * N_))[n4];
    *(float4*)&row_l[j][n4 * 4] = v;
  }
  __syncthreads();
  float bgc[8];
#pragma unroll
  for (int j = 0; j < 8; ++j) bgc[j] = bg[c0 + j];
  float s1[8], s2[8];
#pragma unroll
  for (int j = 0; j < 8; ++j) {
    s1[j] = 0.f;
    s2[j] = 0.f;
  }
  float* outb = out + ((size_t)b * C_ + c0) * N_;
#pragma unroll
  for (int s = 0; s < 4; ++s) {
    const int n = tid + 256 * s;
    const int* nn_ = &nb_l[n * K_];
    int idx[K_];
#pragma unroll
    for (int k = 0; k < K_; ++k) idx[k] = nn_[k];
    float a[8];
#pragma unroll
    for (int j = 0; j < 8; ++j) a[j] = row_l[j][n];
#pragma unroll
    for (int k = 0; k < K_; ++k) {
      const int m = idx[k];
#pragma unroll
      for (int j = 0; j < 8; ++j) a[j] += row_l[j][m];
    }
#pragma unroll
    for (int j = 0; j < 8; ++j) {
      float y = fmaf(a[j], 0.099999994f, bgc[j]);
      outb[(size_t)j * N_ + n] = y;
      s1[j] += y;
      s2[j] = fmaf(y, y, s2[j]);
    }
  }
#pragma unroll
  for (int off = 32; off > 0; off >>= 1)
#pragma unroll
    for (int j = 0; j < 8; ++j) {
      s1[j] += __shfl_down(s1[j], off, 64);
      s2[j] += __shfl_down(s2[j], off, 64);
    }
  const int lane = tid & 63, wid = tid >> 6;
  if (lane == 0)
#pragma unroll
    for (int j = 0; j < 8; ++j) {
      red[0][j][wid] = s1[j];
      red[1][j][wid] = s2[j];
    }
  __syncthreads();
  if (tid < 16) {
    const int j = tid & 7, which = tid >> 3;
    float v = red[which][j][0] + red[which][j][1] + red[which][j][2] + red[which][j][3];
    atomicAdd(&stats[which * C_ + c0 + j], v);
  }
}

// ---------------- BN (batch stats) + tanh-GELU + residual ----------------
__global__ void k_bn(const float* __restrict__ x, const float* __restrict__ gamma,
                     const float* __restrict__ beta, const float* __restrict__ stats,
                     float* __restrict__ out) {
  const int f = blockIdx.x * blockDim.x + threadIdx.x;
  const int e = f * 4;
  const int c = (e >> 10) % C_;
  const float inv = 1.f / 16384.f;
  const float mu = stats[c] * inv;
  const float var = fmaf(-mu, mu, stats[C_ + c] * inv);
  const float sc = gamma[c] * rsqrtf(var + 1e-5f);
  const float sh = fmaf(-mu, sc, beta[c]);
  float4 y = ((const float4*)out)[f];
  float4 xv = ((const float4*)x)[f];
  auto gl = [](float z) {
    float z3 = z * z * z;
    float t = 0.7978845608028654f * fmaf(0.044715f, z3, z);
    float th = tanhf(t);
    return 0.5f * z * (1.f + th);
  };
  float4 o;
  o.x = gl(fmaf(y.x, sc, sh)) + xv.x;
  o.y = gl(fmaf(y.y, sc, sh)) + xv.y;
  o.z = gl(fmaf(y.z, sc, sh)) + xv.z;
  o.w = gl(fmaf(y.w, sc, sh)) + xv.w;
  ((float4*)out)[f] = o;
}

extern "C" void kernel_launch(void* const* d_in, const int* in_sizes, int n_in,
                              void* d_out, int out_size, void* d_ws, size_t ws_size,
                              hipStream_t stream) {
  const float* x = (const float*)d_in[0];
  const float* Wg = (const float*)d_in[1];
  const float* bg = (const float*)d_in[2];
  const float* gamma = (const float*)d_in[3];
  const float* beta = (const float*)d_in[4];
  float* out = (float*)d_out;

  char* ws = (char*)d_ws;
  ushort* xhT = (ushort*)ws;                  // @0          12,582,912
  ushort* xlT = (ushort*)(ws + 12582912);     //             12,582,912
  ushort* WgH = (ushort*)(ws + 25165824);     //                294,912
  ushort* WgL = (ushort*)(ws + 25460736);     //                294,912
  float* sq = (float*)(ws + 25755648);        //                 65,536
  u64* part = (u64*)(ws + 25821184);          // 9,437,184
  float* xw = (float*)(ws + 25821184 + 9437184);           // 25,165,824 (disjoint: part
                                                           // still live when xw written)
  int* nbr = (int*)(ws + 25821184 + 9437184 + 25165824);   //      589,824
  float* stats = (float*)(ws + 25821184 + 9437184 + 25165824 + 589824);  // 3,072

  k_cvt<<<656, 256, 0, stream>>>(x, Wg, xhT, xlT, sq, WgH, WgL, stats);
  k_gram<<<576, 256, 0, stream>>>(xhT, xlT, sq, part);
  k_xw<<<768, 256, 0, stream>>>(xhT, xlT, WgH, WgL, xw);
  k_mrg<<<64, 256, 0, stream>>>(part, nbr, 0);
  k_agg<<<B_ * (C_ / 8), 256, 0, stream>>>(xw, nbr, bg, out, stats);
  k_bn<<<6144, 256, 0, stream>>>(x, gamma, beta, stats, out);
}